// Round 6
// baseline (168.083 us; speedup 1.0000x reference)
//
#include <hip/hip_runtime.h>
#include <math.h>

#define BB 8
#define PP 10
#define SS 160
#define FXD 11
#define DD 64
#define DFF 256
#define NROW (BB*PP*SS)   /* 12800 */
#define NBP  (BB*PP)      /* 80 */

// d_out layout (floats): pred | pred_resampl | K | V | R | attn
#define OFF_PRED  0
#define OFF_PREDR 12800
#define OFF_K     25600
#define OFF_V     844800
#define OFF_R     1664000
#define OFF_ATTN  2483200

__device__ __forceinline__ void fma4(float4& acc, float s, const float4& b){
  acc.x += s*b.x; acc.y += s*b.y; acc.z += s*b.z; acc.w += s*b.w;
}
__device__ __forceinline__ float wred_sum(float v){
#pragma unroll
  for (int m = 32; m >= 1; m >>= 1) v += __shfl_xor(v, m, 64);
  return v;
}
__device__ __forceinline__ float wred_max(float v){
#pragma unroll
  for (int m = 32; m >= 1; m >>= 1) v = fmaxf(v, __shfl_xor(v, m, 64));
  return v;
}
// bf16 pack/unpack (RTN-even)
__device__ __forceinline__ unsigned f2bf(float f){
  unsigned u = __float_as_uint(f);
  return (u + 0x7fffu + ((u >> 16) & 1u)) >> 16;
}
__device__ __forceinline__ unsigned packbf2(float x, float y){
  return f2bf(x) | (f2bf(y) << 16);
}
__device__ __forceinline__ float bflo(unsigned u){ return __uint_as_float(u << 16); }
__device__ __forceinline__ float bfhi(unsigned u){ return __uint_as_float(u & 0xffff0000u); }

// ---------------------------------------------------------------------------
// Fused proj + QKV. 32-row tiles, 400 blocks. Register double-buffer of the
// next weight matrix overlaps global fetch with LDS compute.
// ---------------------------------------------------------------------------
__global__ __launch_bounds__(256) void k_xqkv(const float* __restrict__ inp,
    const float* __restrict__ Wp, const float* __restrict__ bpj,
    const float* __restrict__ Wq, const float* __restrict__ bq,
    const float* __restrict__ Wk, const float* __restrict__ bk,
    const float* __restrict__ Wv, const float* __restrict__ bv,
    float* __restrict__ x, float* __restrict__ Q,
    float* __restrict__ Kc, float* __restrict__ Vc){
  __shared__ __align__(16) float ins[32*12];
  __shared__ __align__(16) float xs[32*68];
  __shared__ __align__(16) float wsb[64*64];
  int tid = threadIdx.x;
  int row0 = blockIdx.x * 32;
  for (int i = tid; i < 32*FXD; i += 256){
    int r = i / FXD, f = i - r*FXD;
    ins[r*12 + f] = inp[row0*FXD + i];
  }
  __syncthreads();
  int tc = tid & 15, tr = tid >> 4;
  int r0 = tr*2, r1 = r0 + 1;
  // x = (inp @ Wp + bp) * 8  (2 rows per thread)
  {
    float4 a0 = make_float4(0.f,0.f,0.f,0.f);
    float4 a1 = make_float4(0.f,0.f,0.f,0.f);
#pragma unroll
    for (int f = 0; f < FXD; ++f){
      float4 w4 = *(const float4*)&Wp[f*64 + tc*4];
      fma4(a0, ins[r0*12 + f], w4);
      fma4(a1, ins[r1*12 + f], w4);
    }
    float4 bp4 = *(const float4*)&bpj[tc*4];
    float4 x0 = make_float4((a0.x+bp4.x)*8.f,(a0.y+bp4.y)*8.f,(a0.z+bp4.z)*8.f,(a0.w+bp4.w)*8.f);
    float4 x1 = make_float4((a1.x+bp4.x)*8.f,(a1.y+bp4.y)*8.f,(a1.z+bp4.z)*8.f,(a1.w+bp4.w)*8.f);
    *(float4*)&xs[r0*68 + tc*4] = x0;
    *(float4*)&xs[r1*68 + tc*4] = x1;
    *(float4*)&x[(row0+r0)*64 + tc*4] = x0;
    *(float4*)&x[(row0+r1)*64 + tc*4] = x1;
  }
  const float* Wt[3] = {Wq, Wk, Wv};
  const float* bt[3] = {bq, bk, bv};
  float* Ot[3] = {Q, Kc, Vc};
  float4 wreg[4];
  {
    const float4* Wsrc = (const float4*)Wt[0];
#pragma unroll
    for (int i = 0; i < 4; ++i) wreg[i] = Wsrc[tid + i*256];
  }
  __syncthreads();                  // xs visible
  for (int w = 0; w < 3; ++w){
    {
      float4* Wdst = (float4*)wsb;
#pragma unroll
      for (int i = 0; i < 4; ++i) Wdst[tid + i*256] = wreg[i];
    }
    __syncthreads();                // wsb ready
    if (w < 2){
      const float4* Wsrc = (const float4*)Wt[w+1];
#pragma unroll
      for (int i = 0; i < 4; ++i) wreg[i] = Wsrc[tid + i*256];
    }
    float4 c0 = make_float4(0.f,0.f,0.f,0.f);
    float4 c1 = make_float4(0.f,0.f,0.f,0.f);
#pragma unroll 4
    for (int k4 = 0; k4 < 16; ++k4){
      float4 x0 = *(const float4*)&xs[r0*68 + k4*4];
      float4 x1 = *(const float4*)&xs[r1*68 + k4*4];
      float4 w0 = *(const float4*)&wsb[(k4*4+0)*64 + tc*4];
      float4 w1 = *(const float4*)&wsb[(k4*4+1)*64 + tc*4];
      float4 w2 = *(const float4*)&wsb[(k4*4+2)*64 + tc*4];
      float4 w3 = *(const float4*)&wsb[(k4*4+3)*64 + tc*4];
      fma4(c0, x0.x, w0); fma4(c0, x0.y, w1); fma4(c0, x0.z, w2); fma4(c0, x0.w, w3);
      fma4(c1, x1.x, w0); fma4(c1, x1.y, w1); fma4(c1, x1.z, w2); fma4(c1, x1.w, w3);
    }
    float4 bb = *(const float4*)&bt[w][tc*4];
    *(float4*)&Ot[w][(row0+r0)*64 + tc*4] =
      make_float4(c0.x+bb.x, c0.y+bb.y, c0.z+bb.z, c0.w+bb.w);
    *(float4*)&Ot[w][(row0+r1)*64 + tc*4] =
      make_float4(c1.x+bb.x, c1.y+bb.y, c1.z+bb.z, c1.w+bb.w);
    __syncthreads();                // wsb readers done before next overwrite
  }
}

// ---------------------------------------------------------------------------
// Mega-fused attention+FFN with uniform work: each block handles the chunk
// pair (p, 19-p) of 8 rows each. Grid (80 bp, 10 pairs) = 800 uniform blocks.
// LDS ~40KB -> 4 blocks/CU, all 800 resident, no tail.
// ---------------------------------------------------------------------------
__global__ __launch_bounds__(256, 4) void k_attn_ffn(const float* __restrict__ Q,
    const float* __restrict__ Kout, const float* __restrict__ Vout,
    const float* __restrict__ Wo, const float* __restrict__ bo,
    const float* __restrict__ g1, const float* __restrict__ b1l,
    const float* __restrict__ x,
    const float* __restrict__ W1, const float* __restrict__ b1,
    const float* __restrict__ W2, const float* __restrict__ b2,
    const float* __restrict__ g2, const float* __restrict__ b2l,
    const float* __restrict__ Wf, const float* __restrict__ bf,
    float* __restrict__ attn, float* __restrict__ R,
    float* __restrict__ pred, float* __restrict__ predr){
  // union: phases A-C: ks2(21120B) | qs(4352B) | ps(10496B) = 35968B
  //        FFN:        as(16640B)  | red(16384B)           = 33024B
  __shared__ __align__(16) unsigned char smem[35968];
  __shared__ __align__(16) float os[16*68];           // LN1 out (residual)
  unsigned* ks2 = (unsigned*)smem;                    // 160 x 33 u32 (bf16x2)
  float* qs = (float*)(smem + 21120);                 // 16 x 68
  float* ps = (float*)(smem + 25472);                 // 16 x 164
  float* Zs  = qs;                                    // 16 x 68 (after phase A)
  float* zos = ps;                                    // 16 x 68 (after phase B)
  float* as  = (float*)smem;                          // 16 x 260 (FFN)
  float* red = (float*)(smem + 16640);                // 4096 (FFN split-K)

  int tid = threadIdx.x;
  int bp = blockIdx.x, p = blockIdx.y;
  int t0_lo = p*8,        tend_lo = t0_lo + 8;
  int t0_hi = (19 - p)*8, tend_hi = t0_hi + 8;
  const float* Kb = Kout + bp*(SS*DD);
  const float* Vb = Vout + bp*(SS*DD);
  const float* Qb = Q + bp*(SS*DD);
  float* Ab = attn + bp*(SS*SS);

  // ---- stage K[0..tend_hi) packed bf16; Q rows (8 lo + 8 hi) ----
  for (int i = tid; i < tend_hi*16; i += 256){
    int r = i >> 4, e4 = i & 15;
    float4 kv = *(const float4*)&Kb[r*64 + e4*4];
    int base = r*33 + e4*2;
    ks2[base]   = packbf2(kv.x, kv.y);
    ks2[base+1] = packbf2(kv.z, kv.w);
  }
  {
    int r = tid >> 4, e4 = (tid & 15)*4;
    int src = (r < 8) ? (t0_lo + r) : (t0_hi + r - 8);
    *(float4*)&qs[r*68 + e4] = *(const float4*)&Qb[src*64 + e4];
  }
  __syncthreads();

  int lane = tid & 63, wid = tid >> 6;
  int s0 = lane, s1 = lane + 64, s2 = lane + 128;
  int a0 = s0*33, a1 = s1*33, a2 = (s2 < SS ? s2 : 0)*33;

  // ---- phase A: logits + softmax. waves 0,1 -> lo chunk; 2,3 -> hi ----
  {
    bool isHi = (wid >= 2);
    int chunkT0 = isHi ? t0_hi : t0_lo;
    int ngc = (chunkT0 >> 6) + 1;            // s-groups needed (uniform/chunk)
    int rbase = (wid & 1)*4;                 // rows within chunk
    int qrow0 = (isHi ? 8 : 0) + rbase;      // qs/ps row base
    float acc[4][3] = {};
#pragma unroll 4
    for (int e4 = 0; e4 < 16; ++e4){
      int e2 = e4*2;
      unsigned u00 = ks2[a0+e2], u01 = ks2[a0+e2+1];
      float k00 = bflo(u00), k01 = bfhi(u00), k02 = bflo(u01), k03 = bfhi(u01);
      float k10=0,k11=0,k12=0,k13=0,k20=0,k21=0,k22=0,k23=0;
      if (ngc > 1){ unsigned u10 = ks2[a1+e2], u11 = ks2[a1+e2+1];
        k10 = bflo(u10); k11 = bfhi(u10); k12 = bflo(u11); k13 = bfhi(u11); }
      if (ngc > 2){ unsigned u20 = ks2[a2+e2], u21 = ks2[a2+e2+1];
        k20 = bflo(u20); k21 = bfhi(u20); k22 = bflo(u21); k23 = bfhi(u21); }
#pragma unroll
      for (int tt = 0; tt < 4; ++tt){
        float4 q4 = *(const float4*)&qs[(qrow0+tt)*68 + e4*4];
        acc[tt][0] += q4.x*k00 + q4.y*k01 + q4.z*k02 + q4.w*k03;
        if (ngc > 1) acc[tt][1] += q4.x*k10 + q4.y*k11 + q4.z*k12 + q4.w*k13;
        if (ngc > 2) acc[tt][2] += q4.x*k20 + q4.y*k21 + q4.z*k22 + q4.w*k23;
      }
    }
#pragma unroll
    for (int tt = 0; tt < 4; ++tt){
      int t = chunkT0 + rbase + tt;
      int prow = qrow0 + tt;
      bool v0 = (s0 <= t), v1 = (s1 <= t), v2 = (s2 <= t) && (s2 < SS);
      float l0 = v0 ? acc[tt][0]*0.125f : -INFINITY;
      float l1 = v1 ? acc[tt][1]*0.125f : -INFINITY;
      float l2 = v2 ? acc[tt][2]*0.125f : -INFINITY;
      float m = wred_max(fmaxf(l0, fmaxf(l1, l2)));
      float e0 = v0 ? __expf(l0-m) : 0.f;
      float e1 = v1 ? __expf(l1-m) : 0.f;
      float e2 = v2 ? __expf(l2-m) : 0.f;
      float inv = 1.0f / wred_sum(e0+e1+e2);
      float p0 = e0*inv, p1 = e1*inv, p2 = e2*inv;
      float* Arow = &Ab[t*SS];
      Arow[s0] = p0; ps[prow*164 + s0] = p0;
      Arow[s1] = p1; ps[prow*164 + s1] = p1;
      if (s2 < SS){ Arow[s2] = p2; ps[prow*164 + s2] = p2; }
    }
  }
  __syncthreads();

  // ---- phase B: Z(16x64) = P @ V ----
  int tc = tid & 15, tr = tid >> 4;
  {
    int send = (tr < 8) ? tend_lo : tend_hi;   // wave-uniform
    float4 z = make_float4(0.f,0.f,0.f,0.f);
    int pb = tr*164;
#pragma unroll 4
    for (int s = 0; s < send; ++s){
      float pv = ps[pb + s];
      float4 v4 = *(const float4*)&Vb[s*64 + tc*4];
      fma4(z, pv, v4);
    }
    *(float4*)&Zs[tr*68 + tc*4] = z;
  }
  __syncthreads();

  // ---- phase C: zo = Z@Wo + bo + x ----
  {
    float4 acc = make_float4(0.f,0.f,0.f,0.f);
#pragma unroll 4
    for (int k4 = 0; k4 < 16; ++k4){
      float4 z4 = *(const float4*)&Zs[tr*68 + k4*4];
      float4 w0 = *(const float4*)&Wo[(k4*4+0)*64 + tc*4];
      float4 w1 = *(const float4*)&Wo[(k4*4+1)*64 + tc*4];
      float4 w2 = *(const float4*)&Wo[(k4*4+2)*64 + tc*4];
      float4 w3 = *(const float4*)&Wo[(k4*4+3)*64 + tc*4];
      fma4(acc, z4.x, w0); fma4(acc, z4.y, w1);
      fma4(acc, z4.z, w2); fma4(acc, z4.w, w3);
    }
    int grow = bp*SS + ((tr < 8) ? (t0_lo + tr) : (t0_hi + tr - 8));
    float4 bo4 = *(const float4*)&bo[tc*4];
    float4 xr  = *(const float4*)&x[grow*64 + tc*4];
    *(float4*)&zos[tr*68 + tc*4] = make_float4(acc.x+bo4.x+xr.x, acc.y+bo4.y+xr.y,
                                               acc.z+bo4.z+xr.z, acc.w+bo4.w+xr.w);
  }
  __syncthreads();

  // ---- LN1 -> os ----
  for (int r = wid; r < 16; r += 4){
    float h = zos[r*68 + lane];
    float mu = wred_sum(h) * (1.f/64.f);
    float dv = h - mu;
    float var = wred_sum(dv*dv) * (1.f/64.f);
    os[r*68 + lane] = g1[lane]*dv*rsqrtf(var + 1e-6f) + b1l[lane];
  }
  __syncthreads();

  // ---- FFN1: as = relu(os @ W1 + b1)  (16x256) ----
  {
    int fc = tid & 63, fr = tid >> 6;
    float4 acc[4];
#pragma unroll
    for (int i = 0; i < 4; ++i) acc[i] = make_float4(0.f,0.f,0.f,0.f);
#pragma unroll 2
    for (int k4 = 0; k4 < 16; ++k4){
      float4 a0 = *(const float4*)&os[(fr*4+0)*68 + k4*4];
      float4 a1 = *(const float4*)&os[(fr*4+1)*68 + k4*4];
      float4 a2 = *(const float4*)&os[(fr*4+2)*68 + k4*4];
      float4 a3 = *(const float4*)&os[(fr*4+3)*68 + k4*4];
      float4 w0 = *(const float4*)&W1[(k4*4+0)*256 + fc*4];
      float4 w1 = *(const float4*)&W1[(k4*4+1)*256 + fc*4];
      float4 w2 = *(const float4*)&W1[(k4*4+2)*256 + fc*4];
      float4 w3 = *(const float4*)&W1[(k4*4+3)*256 + fc*4];
      fma4(acc[0], a0.x, w0); fma4(acc[0], a0.y, w1); fma4(acc[0], a0.z, w2); fma4(acc[0], a0.w, w3);
      fma4(acc[1], a1.x, w0); fma4(acc[1], a1.y, w1); fma4(acc[1], a1.z, w2); fma4(acc[1], a1.w, w3);
      fma4(acc[2], a2.x, w0); fma4(acc[2], a2.y, w1); fma4(acc[2], a2.z, w2); fma4(acc[2], a2.w, w3);
      fma4(acc[3], a3.x, w0); fma4(acc[3], a3.y, w1); fma4(acc[3], a3.z, w2); fma4(acc[3], a3.w, w3);
    }
    float4 bb = *(const float4*)&b1[fc*4];
#pragma unroll
    for (int i = 0; i < 4; ++i)
      *(float4*)&as[(fr*4+i)*260 + fc*4] = make_float4(
        fmaxf(acc[i].x+bb.x,0.f), fmaxf(acc[i].y+bb.y,0.f),
        fmaxf(acc[i].z+bb.z,0.f), fmaxf(acc[i].w+bb.w,0.f));
  }
  __syncthreads();

  // ---- FFN2: 16x64, K=256 split-K x4 ----
  {
    int kp = wid;
    int tc2 = lane & 15, tr2 = lane >> 4;
    float4 acc[4];
#pragma unroll
    for (int i = 0; i < 4; ++i) acc[i] = make_float4(0.f,0.f,0.f,0.f);
    int kbase = kp*64;
#pragma unroll 2
    for (int kk4 = 0; kk4 < 16; ++kk4){
      int k = kbase + kk4*4;
      float4 a0 = *(const float4*)&as[(tr2*4+0)*260 + k];
      float4 a1 = *(const float4*)&as[(tr2*4+1)*260 + k];
      float4 a2 = *(const float4*)&as[(tr2*4+2)*260 + k];
      float4 a3 = *(const float4*)&as[(tr2*4+3)*260 + k];
      float4 w0 = *(const float4*)&W2[(k+0)*64 + tc2*4];
      float4 w1 = *(const float4*)&W2[(k+1)*64 + tc2*4];
      float4 w2 = *(const float4*)&W2[(k+2)*64 + tc2*4];
      float4 w3 = *(const float4*)&W2[(k+3)*64 + tc2*4];
      fma4(acc[0], a0.x, w0); fma4(acc[0], a0.y, w1); fma4(acc[0], a0.z, w2); fma4(acc[0], a0.w, w3);
      fma4(acc[1], a1.x, w0); fma4(acc[1], a1.y, w1); fma4(acc[1], a1.z, w2); fma4(acc[1], a1.w, w3);
      fma4(acc[2], a2.x, w0); fma4(acc[2], a2.y, w1); fma4(acc[2], a2.z, w2); fma4(acc[2], a2.w, w3);
      fma4(acc[3], a3.x, w0); fma4(acc[3], a3.y, w1); fma4(acc[3], a3.z, w2); fma4(acc[3], a3.w, w3);
    }
#pragma unroll
    for (int i = 0; i < 4; ++i)
      *(float4*)&red[kp*1024 + (tr2*4+i)*64 + tc2*4] = acc[i];
  }
  __syncthreads();

  // ---- reduce + residual + LN2 -> R, pred ----
  {
    float wfv = Wf[lane];
    float bfv = bf[0];
#pragma unroll
    for (int j = 0; j < 4; ++j){
      int r = wid*4 + j;
      float h = red[r*64+lane] + red[1024 + r*64+lane]
              + red[2048 + r*64+lane] + red[3072 + r*64+lane]
              + b2[lane] + os[r*68 + lane];
      float mu = wred_sum(h) * (1.f/64.f);
      float dv = h - mu;
      float var = wred_sum(dv*dv) * (1.f/64.f);
      float rv = g2[lane]*dv*rsqrtf(var + 1e-6f) + b2l[lane];
      int grow = bp*SS + ((r < 8) ? (t0_lo + r) : (t0_hi + r - 8));
      R[grow*64 + lane] = rv;
      float pw = wred_sum(rv * wfv);
      if (lane == 0){ pred[grow] = pw + bfv; predr[grow] = pw + bfv; }
    }
  }
}

extern "C" void kernel_launch(void* const* d_in, const int* in_sizes, int n_in,
                              void* d_out, int out_size, void* d_ws, size_t ws_size,
                              hipStream_t stream){
  const float* inputs = (const float*)d_in[0];
  const float* Wp  = (const float*)d_in[2];
  const float* bpj = (const float*)d_in[3];
  const float* Wq  = (const float*)d_in[4];  const float* bq  = (const float*)d_in[5];
  const float* Wk  = (const float*)d_in[6];  const float* bk  = (const float*)d_in[7];
  const float* Wv  = (const float*)d_in[8];  const float* bv  = (const float*)d_in[9];
  const float* Wo  = (const float*)d_in[10]; const float* bo  = (const float*)d_in[11];
  const float* g1  = (const float*)d_in[12]; const float* b1l = (const float*)d_in[13];
  const float* W1  = (const float*)d_in[14]; const float* b1  = (const float*)d_in[15];
  const float* W2  = (const float*)d_in[16]; const float* b2  = (const float*)d_in[17];
  const float* g2  = (const float*)d_in[18]; const float* b2l = (const float*)d_in[19];
  const float* Wf  = (const float*)d_in[20]; const float* bf  = (const float*)d_in[21];

  float* outp = (float*)d_out;
  float* ws   = (float*)d_ws;
  float* x    = ws;                 // 819200 floats
  float* Qw   = ws + 819200;        // 819200

  float* pred  = outp + OFF_PRED;
  float* predr = outp + OFF_PREDR;
  float* Kc    = outp + OFF_K;
  float* Vc    = outp + OFF_V;
  float* Rr    = outp + OFF_R;
  float* attn  = outp + OFF_ATTN;

  k_xqkv<<<NROW/32, 256, 0, stream>>>(inputs, Wp, bpj, Wq, bq, Wk, bk, Wv, bv,
                                      x, Qw, Kc, Vc);
  k_attn_ffn<<<dim3(NBP, 10), 256, 0, stream>>>(Qw, Kc, Vc, Wo, bo, g1, b1l, x,
                                                W1, b1, W2, b2, g2, b2l, Wf, bf,
                                                attn, Rr, pred, predr);
}

// Round 7
// 161.513 us; speedup vs baseline: 1.0407x; 1.0407x over previous
//
#include <hip/hip_runtime.h>
#include <math.h>

#define BB 8
#define PP 10
#define SS 160
#define FXD 11
#define DD 64
#define DFF 256
#define NROW (BB*PP*SS)   /* 12800 */
#define NBP  (BB*PP)      /* 80 */

// d_out layout (floats): pred | pred_resampl | K | V | R | attn
#define OFF_PRED  0
#define OFF_PREDR 12800
#define OFF_K     25600
#define OFF_V     844800
#define OFF_R     1664000
#define OFF_ATTN  2483200

__device__ __forceinline__ void fma4(float4& acc, float s, const float4& b){
  acc.x += s*b.x; acc.y += s*b.y; acc.z += s*b.z; acc.w += s*b.w;
}
template<int N>
__device__ __forceinline__ void wred_sum_n(float (&v)[N]){
#pragma unroll
  for (int m = 32; m >= 1; m >>= 1){
#pragma unroll
    for (int i = 0; i < N; ++i) v[i] += __shfl_xor(v[i], m, 64);
  }
}
template<int N>
__device__ __forceinline__ void wred_max_n(float (&v)[N]){
#pragma unroll
  for (int m = 32; m >= 1; m >>= 1){
#pragma unroll
    for (int i = 0; i < N; ++i) v[i] = fmaxf(v[i], __shfl_xor(v[i], m, 64));
  }
}
// bf16 pack/unpack (RTN-even)
__device__ __forceinline__ unsigned f2bf(float f){
  unsigned u = __float_as_uint(f);
  return (u + 0x7fffu + ((u >> 16) & 1u)) >> 16;
}
__device__ __forceinline__ unsigned packbf2(float x, float y){
  return f2bf(x) | (f2bf(y) << 16);
}
__device__ __forceinline__ float bflo(unsigned u){ return __uint_as_float(u << 16); }
__device__ __forceinline__ float bfhi(unsigned u){ return __uint_as_float(u & 0xffff0000u); }

// ---------------------------------------------------------------------------
// Fused proj + QKV. 16-row tiles, 800 blocks. All three weight matrices staged
// ONCE as packed bf16x2 (24KB LDS), 2 barriers total, ~30KB LDS -> 5 blocks/CU.
// ---------------------------------------------------------------------------
__global__ __launch_bounds__(256) void k_xqkv(const float* __restrict__ inp,
    const float* __restrict__ Wp, const float* __restrict__ bpj,
    const float* __restrict__ Wq, const float* __restrict__ bq,
    const float* __restrict__ Wk, const float* __restrict__ bk,
    const float* __restrict__ Wv, const float* __restrict__ bv,
    float* __restrict__ x, float* __restrict__ Q,
    float* __restrict__ Kc, float* __restrict__ Vc){
  __shared__ __align__(16) float ins[16*12];
  __shared__ __align__(16) float xs[16*68];
  __shared__ __align__(16) unsigned ws2[3*32*64];   // bf16x2 packed along K
  int tid = threadIdx.x;
  int row0 = blockIdx.x * 16;
  const float* Wt[3] = {Wq, Wk, Wv};
  // stage inputs
  for (int i = tid; i < 16*FXD; i += 256){
    int r = i / FXD, f = i - r*FXD;
    ins[r*12 + f] = inp[row0*FXD + i];
  }
  // pack all 3 weight matrices: 1536 quad-tasks, 6 per thread, all loads in flight
#pragma unroll
  for (int i = 0; i < 6; ++i){
    int idx = tid + i*256;               // 0..1535
    int mat = idx >> 9, rem = idx & 511;
    int m = rem >> 4, c4 = (rem & 15)*4;
    const float* W = Wt[mat];
    float4 wlo = *(const float4*)&W[(2*m)*64 + c4];
    float4 whi = *(const float4*)&W[(2*m+1)*64 + c4];
    unsigned* dst = &ws2[mat*2048 + m*64 + c4];
    dst[0] = packbf2(wlo.x, whi.x); dst[1] = packbf2(wlo.y, whi.y);
    dst[2] = packbf2(wlo.z, whi.z); dst[3] = packbf2(wlo.w, whi.w);
  }
  __syncthreads();
  int tc = tid & 15, tr = tid >> 4;
  // x = (inp @ Wp + bp) * 8  (Wp is 2.8KB, L1-hot across 800 blocks)
  {
    float4 a = make_float4(0.f,0.f,0.f,0.f);
#pragma unroll
    for (int f = 0; f < FXD; ++f){
      float v = ins[tr*12 + f];
      float4 w4 = *(const float4*)&Wp[f*64 + tc*4];
      fma4(a, v, w4);
    }
    float4 bp4 = *(const float4*)&bpj[tc*4];
    float4 xv = make_float4((a.x+bp4.x)*8.f, (a.y+bp4.y)*8.f,
                            (a.z+bp4.z)*8.f, (a.w+bp4.w)*8.f);
    *(float4*)&xs[tr*68 + tc*4] = xv;
    *(float4*)&x[(row0+tr)*64 + tc*4] = xv;
  }
  __syncthreads();
  const float* bt[3] = {bq, bk, bv};
  float* Ot[3] = {Q, Kc, Vc};
#pragma unroll
  for (int w = 0; w < 3; ++w){
    const unsigned* wsm = &ws2[w*2048];
    float4 acc = make_float4(0.f,0.f,0.f,0.f);
#pragma unroll 4
    for (int m = 0; m < 32; ++m){
      float2 xp = *(const float2*)&xs[tr*68 + 2*m];
      uint4 u = *(const uint4*)&wsm[m*64 + tc*4];
      float4 wlo = make_float4(bflo(u.x), bflo(u.y), bflo(u.z), bflo(u.w));
      float4 whi = make_float4(bfhi(u.x), bfhi(u.y), bfhi(u.z), bfhi(u.w));
      fma4(acc, xp.x, wlo); fma4(acc, xp.y, whi);
    }
    float4 bb = *(const float4*)&bt[w][tc*4];
    *(float4*)&Ot[w][(row0+tr)*64 + tc*4] =
      make_float4(acc.x+bb.x, acc.y+bb.y, acc.z+bb.z, acc.w+bb.w);
  }
}

// ---------------------------------------------------------------------------
// Mega-fused attention+FFN; chunk pair (p, 19-p), 8 rows each -> uniform work.
// Grid (80 bp, 10 pairs) = 800 blocks, ~40KB LDS -> 4 blocks/CU.
// All wave reductions interleaved (multi-chain butterflies) for ILP.
// ---------------------------------------------------------------------------
__global__ __launch_bounds__(256, 4) void k_attn_ffn(const float* __restrict__ Q,
    const float* __restrict__ Kout, const float* __restrict__ Vout,
    const float* __restrict__ Wo, const float* __restrict__ bo,
    const float* __restrict__ g1, const float* __restrict__ b1l,
    const float* __restrict__ x,
    const float* __restrict__ W1, const float* __restrict__ b1,
    const float* __restrict__ W2, const float* __restrict__ b2,
    const float* __restrict__ g2, const float* __restrict__ b2l,
    const float* __restrict__ Wf, const float* __restrict__ bf,
    float* __restrict__ attn, float* __restrict__ R,
    float* __restrict__ pred, float* __restrict__ predr){
  __shared__ __align__(16) unsigned char smem[35968];
  __shared__ __align__(16) float os[16*68];           // LN1 out (residual)
  unsigned* ks2 = (unsigned*)smem;                    // 160 x 33 u32 (bf16x2)
  float* qs = (float*)(smem + 21120);                 // 16 x 68
  float* ps = (float*)(smem + 25472);                 // 16 x 164
  float* Zs  = qs;                                    // 16 x 68 (after phase A)
  float* zos = ps;                                    // 16 x 68 (after phase B)
  float* as  = (float*)smem;                          // 16 x 260 (FFN)
  float* red = (float*)(smem + 16640);                // 4096 (FFN split-K)

  int tid = threadIdx.x;
  int bp = blockIdx.x, p = blockIdx.y;
  int t0_lo = p*8,        tend_lo = t0_lo + 8;
  int t0_hi = (19 - p)*8, tend_hi = t0_hi + 8;
  const float* Kb = Kout + bp*(SS*DD);
  const float* Vb = Vout + bp*(SS*DD);
  const float* Qb = Q + bp*(SS*DD);
  float* Ab = attn + bp*(SS*SS);

  // ---- stage K[0..tend_hi) packed bf16; Q rows (8 lo + 8 hi) ----
  for (int i = tid; i < tend_hi*16; i += 256){
    int r = i >> 4, e4 = i & 15;
    float4 kv = *(const float4*)&Kb[r*64 + e4*4];
    int base = r*33 + e4*2;
    ks2[base]   = packbf2(kv.x, kv.y);
    ks2[base+1] = packbf2(kv.z, kv.w);
  }
  {
    int r = tid >> 4, e4 = (tid & 15)*4;
    int src = (r < 8) ? (t0_lo + r) : (t0_hi + r - 8);
    *(float4*)&qs[r*68 + e4] = *(const float4*)&Qb[src*64 + e4];
  }
  __syncthreads();

  int lane = tid & 63, wid = tid >> 6;
  int s0 = lane, s1 = lane + 64, s2 = lane + 128;
  int a0 = s0*33, a1 = s1*33, a2 = (s2 < SS ? s2 : 0)*33;

  // ---- phase A: logits + softmax (interleaved reductions) ----
  {
    bool isHi = (wid >= 2);
    int chunkT0 = isHi ? t0_hi : t0_lo;
    int ngc = (chunkT0 >> 6) + 1;
    int rbase = (wid & 1)*4;
    int qrow0 = (isHi ? 8 : 0) + rbase;
    float acc[4][3] = {};
#pragma unroll 4
    for (int e4 = 0; e4 < 16; ++e4){
      int e2 = e4*2;
      unsigned u00 = ks2[a0+e2], u01 = ks2[a0+e2+1];
      float k00 = bflo(u00), k01 = bfhi(u00), k02 = bflo(u01), k03 = bfhi(u01);
      float k10=0,k11=0,k12=0,k13=0,k20=0,k21=0,k22=0,k23=0;
      if (ngc > 1){ unsigned u10 = ks2[a1+e2], u11 = ks2[a1+e2+1];
        k10 = bflo(u10); k11 = bfhi(u10); k12 = bflo(u11); k13 = bfhi(u11); }
      if (ngc > 2){ unsigned u20 = ks2[a2+e2], u21 = ks2[a2+e2+1];
        k20 = bflo(u20); k21 = bfhi(u20); k22 = bflo(u21); k23 = bfhi(u21); }
#pragma unroll
      for (int tt = 0; tt < 4; ++tt){
        float4 q4 = *(const float4*)&qs[(qrow0+tt)*68 + e4*4];
        acc[tt][0] += q4.x*k00 + q4.y*k01 + q4.z*k02 + q4.w*k03;
        if (ngc > 1) acc[tt][1] += q4.x*k10 + q4.y*k11 + q4.z*k12 + q4.w*k13;
        if (ngc > 2) acc[tt][2] += q4.x*k20 + q4.y*k21 + q4.z*k22 + q4.w*k23;
      }
    }
    float mx[4];
#pragma unroll
    for (int tt = 0; tt < 4; ++tt){
      int t = chunkT0 + rbase + tt;
      bool v0 = (s0 <= t), v1 = (s1 <= t), v2 = (s2 <= t) && (s2 < SS);
      acc[tt][0] = v0 ? acc[tt][0]*0.125f : -INFINITY;
      acc[tt][1] = v1 ? acc[tt][1]*0.125f : -INFINITY;
      acc[tt][2] = v2 ? acc[tt][2]*0.125f : -INFINITY;
      mx[tt] = fmaxf(acc[tt][0], fmaxf(acc[tt][1], acc[tt][2]));
    }
    wred_max_n<4>(mx);                 // 4 independent chains
    float ev[4][3], esum[4];
#pragma unroll
    for (int tt = 0; tt < 4; ++tt){
      ev[tt][0] = (acc[tt][0] > -1e30f) ? __expf(acc[tt][0]-mx[tt]) : 0.f;
      ev[tt][1] = (acc[tt][1] > -1e30f) ? __expf(acc[tt][1]-mx[tt]) : 0.f;
      ev[tt][2] = (acc[tt][2] > -1e30f) ? __expf(acc[tt][2]-mx[tt]) : 0.f;
      esum[tt] = ev[tt][0] + ev[tt][1] + ev[tt][2];
    }
    wred_sum_n<4>(esum);               // 4 independent chains
#pragma unroll
    for (int tt = 0; tt < 4; ++tt){
      int t = chunkT0 + rbase + tt;
      int prow = qrow0 + tt;
      float inv = 1.0f / esum[tt];
      float p0 = ev[tt][0]*inv, p1 = ev[tt][1]*inv, p2 = ev[tt][2]*inv;
      float* Arow = &Ab[t*SS];
      Arow[s0] = p0; ps[prow*164 + s0] = p0;
      Arow[s1] = p1; ps[prow*164 + s1] = p1;
      if (s2 < SS){ Arow[s2] = p2; ps[prow*164 + s2] = p2; }
    }
  }
  __syncthreads();

  // ---- phase B: Z(16x64) = P @ V ----
  int tc = tid & 15, tr = tid >> 4;
  {
    int send = (tr < 8) ? tend_lo : tend_hi;   // wave-uniform
    float4 z = make_float4(0.f,0.f,0.f,0.f);
    int pb = tr*164;
#pragma unroll 8
    for (int s = 0; s < send; ++s){
      float pv = ps[pb + s];
      float4 v4 = *(const float4*)&Vb[s*64 + tc*4];
      fma4(z, pv, v4);
    }
    *(float4*)&Zs[tr*68 + tc*4] = z;
  }
  __syncthreads();

  // ---- phase C: zo = Z@Wo + bo + x ----
  {
    float4 acc = make_float4(0.f,0.f,0.f,0.f);
#pragma unroll 4
    for (int k4 = 0; k4 < 16; ++k4){
      float4 z4 = *(const float4*)&Zs[tr*68 + k4*4];
      float4 w0 = *(const float4*)&Wo[(k4*4+0)*64 + tc*4];
      float4 w1 = *(const float4*)&Wo[(k4*4+1)*64 + tc*4];
      float4 w2 = *(const float4*)&Wo[(k4*4+2)*64 + tc*4];
      float4 w3 = *(const float4*)&Wo[(k4*4+3)*64 + tc*4];
      fma4(acc, z4.x, w0); fma4(acc, z4.y, w1);
      fma4(acc, z4.z, w2); fma4(acc, z4.w, w3);
    }
    int grow = bp*SS + ((tr < 8) ? (t0_lo + tr) : (t0_hi + tr - 8));
    float4 bo4 = *(const float4*)&bo[tc*4];
    float4 xr  = *(const float4*)&x[grow*64 + tc*4];
    *(float4*)&zos[tr*68 + tc*4] = make_float4(acc.x+bo4.x+xr.x, acc.y+bo4.y+xr.y,
                                               acc.z+bo4.z+xr.z, acc.w+bo4.w+xr.w);
  }
  __syncthreads();

  // ---- LN1 -> os (single-pass, 8 interleaved chains) ----
  {
    float h[4], s8[8];
#pragma unroll
    for (int j = 0; j < 4; ++j){
      int r = wid + 4*j;
      h[j] = zos[r*68 + lane];
      s8[j] = h[j]; s8[4+j] = h[j]*h[j];
    }
    wred_sum_n<8>(s8);
    float gl = g1[lane], bl = b1l[lane];
#pragma unroll
    for (int j = 0; j < 4; ++j){
      int r = wid + 4*j;
      float mu = s8[j]*(1.f/64.f);
      float var = s8[4+j]*(1.f/64.f) - mu*mu;
      os[r*68 + lane] = gl*(h[j]-mu)*rsqrtf(fmaxf(var,0.f) + 1e-6f) + bl;
    }
  }
  __syncthreads();

  // ---- FFN1: as = relu(os @ W1 + b1)  (16x256) ----
  {
    int fc = tid & 63, fr = tid >> 6;
    float4 acc[4];
#pragma unroll
    for (int i = 0; i < 4; ++i) acc[i] = make_float4(0.f,0.f,0.f,0.f);
#pragma unroll 2
    for (int k4 = 0; k4 < 16; ++k4){
      float4 a0 = *(const float4*)&os[(fr*4+0)*68 + k4*4];
      float4 a1 = *(const float4*)&os[(fr*4+1)*68 + k4*4];
      float4 a2 = *(const float4*)&os[(fr*4+2)*68 + k4*4];
      float4 a3 = *(const float4*)&os[(fr*4+3)*68 + k4*4];
      float4 w0 = *(const float4*)&W1[(k4*4+0)*256 + fc*4];
      float4 w1 = *(const float4*)&W1[(k4*4+1)*256 + fc*4];
      float4 w2 = *(const float4*)&W1[(k4*4+2)*256 + fc*4];
      float4 w3 = *(const float4*)&W1[(k4*4+3)*256 + fc*4];
      fma4(acc[0], a0.x, w0); fma4(acc[0], a0.y, w1); fma4(acc[0], a0.z, w2); fma4(acc[0], a0.w, w3);
      fma4(acc[1], a1.x, w0); fma4(acc[1], a1.y, w1); fma4(acc[1], a1.z, w2); fma4(acc[1], a1.w, w3);
      fma4(acc[2], a2.x, w0); fma4(acc[2], a2.y, w1); fma4(acc[2], a2.z, w2); fma4(acc[2], a2.w, w3);
      fma4(acc[3], a3.x, w0); fma4(acc[3], a3.y, w1); fma4(acc[3], a3.z, w2); fma4(acc[3], a3.w, w3);
    }
    float4 bb = *(const float4*)&b1[fc*4];
#pragma unroll
    for (int i = 0; i < 4; ++i)
      *(float4*)&as[(fr*4+i)*260 + fc*4] = make_float4(
        fmaxf(acc[i].x+bb.x,0.f), fmaxf(acc[i].y+bb.y,0.f),
        fmaxf(acc[i].z+bb.z,0.f), fmaxf(acc[i].w+bb.w,0.f));
  }
  __syncthreads();

  // ---- FFN2: 16x64, K=256 split-K x4 ----
  {
    int kp = wid;
    int tc2 = lane & 15, tr2 = lane >> 4;
    float4 acc[4];
#pragma unroll
    for (int i = 0; i < 4; ++i) acc[i] = make_float4(0.f,0.f,0.f,0.f);
    int kbase = kp*64;
#pragma unroll 2
    for (int kk4 = 0; kk4 < 16; ++kk4){
      int k = kbase + kk4*4;
      float4 a0 = *(const float4*)&as[(tr2*4+0)*260 + k];
      float4 a1 = *(const float4*)&as[(tr2*4+1)*260 + k];
      float4 a2 = *(const float4*)&as[(tr2*4+2)*260 + k];
      float4 a3 = *(const float4*)&as[(tr2*4+3)*260 + k];
      float4 w0 = *(const float4*)&W2[(k+0)*64 + tc2*4];
      float4 w1 = *(const float4*)&W2[(k+1)*64 + tc2*4];
      float4 w2 = *(const float4*)&W2[(k+2)*64 + tc2*4];
      float4 w3 = *(const float4*)&W2[(k+3)*64 + tc2*4];
      fma4(acc[0], a0.x, w0); fma4(acc[0], a0.y, w1); fma4(acc[0], a0.z, w2); fma4(acc[0], a0.w, w3);
      fma4(acc[1], a1.x, w0); fma4(acc[1], a1.y, w1); fma4(acc[1], a1.z, w2); fma4(acc[1], a1.w, w3);
      fma4(acc[2], a2.x, w0); fma4(acc[2], a2.y, w1); fma4(acc[2], a2.z, w2); fma4(acc[2], a2.w, w3);
      fma4(acc[3], a3.x, w0); fma4(acc[3], a3.y, w1); fma4(acc[3], a3.z, w2); fma4(acc[3], a3.w, w3);
    }
#pragma unroll
    for (int i = 0; i < 4; ++i)
      *(float4*)&red[kp*1024 + (tr2*4+i)*64 + tc2*4] = acc[i];
  }
  __syncthreads();

  // ---- reduce + residual + LN2 + pred (interleaved chains) ----
  {
    float wfv = Wf[lane];
    float bfv = bf[0];
    float h[4], s8[8];
#pragma unroll
    for (int j = 0; j < 4; ++j){
      int r = wid*4 + j;
      h[j] = red[r*64+lane] + red[1024 + r*64+lane]
           + red[2048 + r*64+lane] + red[3072 + r*64+lane]
           + b2[lane] + os[r*68 + lane];
      s8[j] = h[j]; s8[4+j] = h[j]*h[j];
    }
    wred_sum_n<8>(s8);
    float g2l = g2[lane], b2ll = b2l[lane];
    float pr[4];
#pragma unroll
    for (int j = 0; j < 4; ++j){
      int r = wid*4 + j;
      float mu = s8[j]*(1.f/64.f);
      float var = s8[4+j]*(1.f/64.f) - mu*mu;
      float rv = g2l*(h[j]-mu)*rsqrtf(fmaxf(var,0.f) + 1e-6f) + b2ll;
      int grow = bp*SS + ((r < 8) ? (t0_lo + r) : (t0_hi + r - 8));
      R[grow*64 + lane] = rv;
      pr[j] = rv * wfv;
    }
    wred_sum_n<4>(pr);
    if (lane == 0){
#pragma unroll
      for (int j = 0; j < 4; ++j){
        int r = wid*4 + j;
        int grow = bp*SS + ((r < 8) ? (t0_lo + r) : (t0_hi + r - 8));
        pred[grow]  = pr[j] + bfv;
        predr[grow] = pr[j] + bfv;
      }
    }
  }
}

extern "C" void kernel_launch(void* const* d_in, const int* in_sizes, int n_in,
                              void* d_out, int out_size, void* d_ws, size_t ws_size,
                              hipStream_t stream){
  const float* inputs = (const float*)d_in[0];
  const float* Wp  = (const float*)d_in[2];
  const float* bpj = (const float*)d_in[3];
  const float* Wq  = (const float*)d_in[4];  const float* bq  = (const float*)d_in[5];
  const float* Wk  = (const float*)d_in[6];  const float* bk  = (const float*)d_in[7];
  const float* Wv  = (const float*)d_in[8];  const float* bv  = (const float*)d_in[9];
  const float* Wo  = (const float*)d_in[10]; const float* bo  = (const float*)d_in[11];
  const float* g1  = (const float*)d_in[12]; const float* b1l = (const float*)d_in[13];
  const float* W1  = (const float*)d_in[14]; const float* b1  = (const float*)d_in[15];
  const float* W2  = (const float*)d_in[16]; const float* b2  = (const float*)d_in[17];
  const float* g2  = (const float*)d_in[18]; const float* b2l = (const float*)d_in[19];
  const float* Wf  = (const float*)d_in[20]; const float* bf  = (const float*)d_in[21];

  float* outp = (float*)d_out;
  float* ws   = (float*)d_ws;
  float* x    = ws;                 // 819200 floats
  float* Qw   = ws + 819200;        // 819200

  float* pred  = outp + OFF_PRED;
  float* predr = outp + OFF_PREDR;
  float* Kc    = outp + OFF_K;
  float* Vc    = outp + OFF_V;
  float* Rr    = outp + OFF_R;
  float* attn  = outp + OFF_ATTN;

  k_xqkv<<<NROW/16, 256, 0, stream>>>(inputs, Wp, bpj, Wq, bq, Wk, bk, Wv, bv,
                                      x, Qw, Kc, Vc);
  k_attn_ffn<<<dim3(NBP, 10), 256, 0, stream>>>(Qw, Kc, Vc, Wo, bo, g1, b1l, x,
                                                W1, b1, W2, b2, g2, b2l, Wf, bf,
                                                attn, Rr, pred, predr);
}

// Round 8
// 138.190 us; speedup vs baseline: 1.2163x; 1.1688x over previous
//
#include <hip/hip_runtime.h>
#include <math.h>

#define BB 8
#define PP 10
#define SS 160
#define FXD 11
#define DD 64
#define DFF 256
#define NROW (BB*PP*SS)   /* 12800 */
#define NBP  (BB*PP)      /* 80 */

// d_out layout (floats): pred | pred_resampl | K | V | R | attn
#define OFF_PRED  0
#define OFF_PREDR 12800
#define OFF_K     25600
#define OFF_V     844800
#define OFF_R     1664000
#define OFF_ATTN  2483200

typedef short short8 __attribute__((ext_vector_type(8)));
typedef float f32x4  __attribute__((ext_vector_type(4)));

__device__ __forceinline__ void fma4(float4& acc, float s, const float4& b){
  acc.x += s*b.x; acc.y += s*b.y; acc.z += s*b.z; acc.w += s*b.w;
}
template<int N>
__device__ __forceinline__ void wred_sum_n(float (&v)[N]){
#pragma unroll
  for (int m = 32; m >= 1; m >>= 1){
#pragma unroll
    for (int i = 0; i < N; ++i) v[i] += __shfl_xor(v[i], m, 64);
  }
}
// quad-local (16-lane) reductions: masks 8..1 keep rows within each quad
template<int N>
__device__ __forceinline__ void qred_sum_n(float (&v)[N]){
#pragma unroll
  for (int m = 8; m >= 1; m >>= 1){
#pragma unroll
    for (int i = 0; i < N; ++i) v[i] += __shfl_xor(v[i], m, 64);
  }
}
template<int N>
__device__ __forceinline__ void qred_max_n(float (&v)[N]){
#pragma unroll
  for (int m = 8; m >= 1; m >>= 1){
#pragma unroll
    for (int i = 0; i < N; ++i) v[i] = fmaxf(v[i], __shfl_xor(v[i], m, 64));
  }
}
// bf16 pack (RTN-even)
__device__ __forceinline__ unsigned f2bf(float f){
  unsigned u = __float_as_uint(f);
  return (u + 0x7fffu + ((u >> 16) & 1u)) >> 16;
}
__device__ __forceinline__ unsigned packbf2(float x, float y){
  return f2bf(x) | (f2bf(y) << 16);
}
__device__ __forceinline__ f32x4 mfma16(uint4 a, uint4 b, f32x4 c){
  union { uint4 u; short8 s; } ua, ub;
  ua.u = a; ub.u = b;
  return __builtin_amdgcn_mfma_f32_16x16x32_bf16(ua.s, ub.s, c, 0, 0, 0);
}

// ---------------------------------------------------------------------------
// Pack weights to bf16 B-fragment layout: wp[n][k/2] = pack(W[k][n], W[k+1][n])
// Regions (u32): wq@0 wk@2048 wv@4096 wo@6144 (64x32 each), w1@8192 (256x32),
// w2@16384 (64x128). Total 24576 u32.
// ---------------------------------------------------------------------------
__global__ __launch_bounds__(256) void k_pack(
    const float* __restrict__ Wq, const float* __restrict__ Wk,
    const float* __restrict__ Wv, const float* __restrict__ Wo,
    const float* __restrict__ W1, const float* __restrict__ W2,
    unsigned* __restrict__ wp){
  int i = blockIdx.x*256 + threadIdx.x;     // 0..24575
  const float* W; int N, K2, base, off;
  if (i < 8192){
    int m = i >> 11; off = i & 2047; N = 64; K2 = 32; base = m*2048;
    W = (m==0)?Wq:((m==1)?Wk:((m==2)?Wv:Wo));
  } else if (i < 16384){
    off = i - 8192; N = 256; K2 = 32; base = 8192; W = W1;
  } else {
    off = i - 16384; N = 64; K2 = 128; base = 16384; W = W2;
  }
  int n = off % N, k2 = off / N;
  wp[base + n*K2 + k2] = packbf2(W[(2*k2)*N + n], W[(2*k2+1)*N + n]);
}

// ---------------------------------------------------------------------------
// proj (fp32) + QKV via MFMA. 16 rows/block, 800 blocks, ~3KB LDS.
// ---------------------------------------------------------------------------
__global__ __launch_bounds__(256) void k_xqkv(const float* __restrict__ inp,
    const float* __restrict__ Wp, const float* __restrict__ bpj,
    const unsigned* __restrict__ wqkvp,
    const float* __restrict__ bq, const float* __restrict__ bk,
    const float* __restrict__ bv,
    float* __restrict__ x, float* __restrict__ Q,
    float* __restrict__ Kc, float* __restrict__ Vc){
  __shared__ __align__(16) float ins[16*12];
  __shared__ __align__(16) unsigned xs2[16*36];   // x packed bf16x2 along k
  int tid = threadIdx.x;
  int row0 = blockIdx.x * 16;
  for (int i = tid; i < 16*FXD; i += 256){
    int r = i / FXD, f = i - r*FXD;
    ins[r*12 + f] = inp[row0*FXD + i];
  }
  __syncthreads();
  int tc = tid & 15, tr = tid >> 4;
  {
    float4 a = make_float4(0.f,0.f,0.f,0.f);
#pragma unroll
    for (int f = 0; f < FXD; ++f){
      float v = ins[tr*12 + f];
      float4 w4 = *(const float4*)&Wp[f*64 + tc*4];
      fma4(a, v, w4);
    }
    float4 bp4 = *(const float4*)&bpj[tc*4];
    float4 xv = make_float4((a.x+bp4.x)*8.f, (a.y+bp4.y)*8.f,
                            (a.z+bp4.z)*8.f, (a.w+bp4.w)*8.f);
    *(float4*)&x[(row0+tr)*64 + tc*4] = xv;
    xs2[tr*36 + tc*2]     = packbf2(xv.x, xv.y);
    xs2[tr*36 + tc*2 + 1] = packbf2(xv.z, xv.w);
  }
  __syncthreads();
  int lane = tid & 63, w = tid >> 6;
  int nl = lane & 15, q = lane >> 4;
  uint4 a0 = *(const uint4*)&xs2[nl*36 + q*4];
  uint4 a1 = *(const uint4*)&xs2[nl*36 + 16 + q*4];
  int n = w*16 + nl;
  const float* bias[3] = {bq, bk, bv};
  float* Out[3] = {Q, Kc, Vc};
#pragma unroll
  for (int mat = 0; mat < 3; ++mat){
    const unsigned* wpm = wqkvp + mat*2048;
    uint4 b0 = *(const uint4*)&wpm[n*32 + q*4];
    uint4 b1 = *(const uint4*)&wpm[n*32 + 16 + q*4];
    f32x4 acc = {0.f,0.f,0.f,0.f};
    acc = mfma16(a0, b0, acc);
    acc = mfma16(a1, b1, acc);
    float bvv = bias[mat][n];
    float* O = Out[mat];
#pragma unroll
    for (int r = 0; r < 4; ++r)
      O[(row0 + q*4 + r)*64 + n] = acc[r] + bvv;
  }
}

// ---------------------------------------------------------------------------
// Mega-fused attention+FFN, all matmuls on MFMA. 16 t-rows per block,
// grid (80,10) = 800 uniform blocks. LDS arena 35712B -> 4 blocks/CU.
// ---------------------------------------------------------------------------
__global__ __launch_bounds__(256, 4) void k_attn_ffn(const float* __restrict__ Qg,
    const float* __restrict__ Kout, const float* __restrict__ Vout,
    const unsigned* __restrict__ wop,
    const unsigned* __restrict__ w1p, const unsigned* __restrict__ w2p,
    const float* __restrict__ bo,
    const float* __restrict__ g1, const float* __restrict__ b1l,
    const float* __restrict__ x,
    const float* __restrict__ b1, const float* __restrict__ b2,
    const float* __restrict__ g2, const float* __restrict__ b2l,
    const float* __restrict__ Wf, const float* __restrict__ bf,
    float* __restrict__ attn, float* __restrict__ R,
    float* __restrict__ pred, float* __restrict__ predr){
  // Arena (bytes):
  //  [0,23040)      ks2 [160][36]u32  -> vs2 [64][84]u32 -> as2 [16][132]u32
  //  [8448,12800)                                          lnb [16][68]f
  //  [23040,25344)  qs2 [16][36]u32   -> os2 [16][36]u32
  //  [25344,30720)  ps2 [16][84]u32   -> zos [16][68]f
  //  [30720,35072)  zs  [16][68]f     -> os  [16][68]f
  //  [35072,35712)  pmax[80]f, psum[80]f
  __shared__ __align__(16) unsigned char smem[35712];
  unsigned* ks2 = (unsigned*)smem;
  unsigned* vs2 = (unsigned*)smem;
  unsigned* as2 = (unsigned*)smem;
  float*    lnb = (float*)(smem + 8448);
  unsigned* qs2 = (unsigned*)(smem + 23040);
  unsigned* os2 = (unsigned*)(smem + 23040);
  unsigned* ps2 = (unsigned*)(smem + 25344);
  float*    zos = (float*)(smem + 25344);
  float*    zs  = (float*)(smem + 30720);
  float*    os  = (float*)(smem + 30720);
  float*    pmax = (float*)(smem + 35072);
  float*    psum = (float*)(smem + 35392);

  int tid = threadIdx.x;
  int bp = blockIdx.x, c = blockIdx.y;
  int t0 = c*16;
  const float* Kb = Kout + bp*(SS*DD);
  const float* Vb = Vout + bp*(SS*DD);
  const float* Qb = Qg + bp*(SS*DD);
  float* Ab = attn + bp*(SS*SS);

  // ---- stage K (full 160 rows, bf16 pairs along d) + Q chunk ----
  for (int i = tid; i < 2560; i += 256){
    int r = i >> 4, e4 = i & 15;
    float4 kv = *(const float4*)&Kb[r*64 + e4*4];
    unsigned* d = &ks2[r*36 + e4*2];
    d[0] = packbf2(kv.x, kv.y); d[1] = packbf2(kv.z, kv.w);
  }
  for (int i = tid; i < 512; i += 256){
    int r = i >> 5, c2 = i & 31;
    float2 qv = *(const float2*)&Qb[(t0+r)*64 + c2*2];
    qs2[r*36 + c2] = packbf2(qv.x, qv.y);
  }
  __syncthreads();

  int lane = tid & 63, w = tid >> 6;
  int nl = lane & 15, q = lane >> 4;

  // ---- phase A: logits via MFMA (wave w owns tiles w, w+4, w+8) ----
  int ntiles = (w < 2) ? 3 : 2;     // T=10 tiles total
  float lg[3][4], ev[3][4];
  float gm[4], inv[4];
  {
    uint4 aq0 = *(const uint4*)&qs2[nl*36 + q*4];
    uint4 aq1 = *(const uint4*)&qs2[nl*36 + 16 + q*4];
    f32x4 pacc[3];
#pragma unroll
    for (int i = 0; i < 3; ++i){
      pacc[i] = (f32x4){0.f,0.f,0.f,0.f};
      if (i < ntiles){
        int srow = (w + 4*i)*16 + nl;
        uint4 b0 = *(const uint4*)&ks2[srow*36 + q*4];
        uint4 b1 = *(const uint4*)&ks2[srow*36 + 16 + q*4];
        pacc[i] = mfma16(aq0, b0, pacc[i]);
        pacc[i] = mfma16(aq1, b1, pacc[i]);
      }
    }
    float mx[4];
#pragma unroll
    for (int r = 0; r < 4; ++r){
      int t = t0 + q*4 + r;
      float m_ = -INFINITY;
#pragma unroll
      for (int i = 0; i < 3; ++i){
        if (i < ntiles){
          int s = (w + 4*i)*16 + nl;
          float l = (s <= t) ? pacc[i][r]*0.125f : -INFINITY;
          lg[i][r] = l; m_ = fmaxf(m_, l);
        }
      }
      mx[r] = m_;
    }
    qred_max_n<4>(mx);
    if (nl == 0){
#pragma unroll
      for (int r = 0; r < 4; ++r) pmax[(q*4+r)*5 + w] = mx[r];
    }
    __syncthreads();
    float sum[4];
#pragma unroll
    for (int r = 0; r < 4; ++r){
      int row = q*4 + r;
      gm[r] = fmaxf(fmaxf(pmax[row*5+0], pmax[row*5+1]),
                    fmaxf(pmax[row*5+2], pmax[row*5+3]));
      float s_ = 0.f;
#pragma unroll
      for (int i = 0; i < 3; ++i){
        if (i < ntiles){
          ev[i][r] = __expf(lg[i][r] - gm[r]);   // exp(-inf)=0 for masked
          s_ += ev[i][r];
        }
      }
      sum[r] = s_;
    }
    qred_sum_n<4>(sum);
    if (nl == 0){
#pragma unroll
      for (int r = 0; r < 4; ++r) psum[(q*4+r)*5 + w] = sum[r];
    }
    __syncthreads();
#pragma unroll
    for (int r = 0; r < 4; ++r){
      int row = q*4 + r;
      inv[r] = 1.0f / (psum[row*5+0] + psum[row*5+1] +
                       psum[row*5+2] + psum[row*5+3]);
    }
    // P -> attn global (fp32) + ps2 (bf16 pairs along s)
#pragma unroll
    for (int i = 0; i < 3; ++i){
      if (i < ntiles){
        int s = (w + 4*i)*16 + nl;
#pragma unroll
        for (int r = 0; r < 4; ++r){
          int t = t0 + q*4 + r;
          float p = ev[i][r] * inv[r];
          Ab[t*SS + s] = p;
          float pn = __shfl_xor(p, 1, 64);
          if (!(nl & 1))
            ps2[(q*4+r)*84 + (w+4*i)*8 + (nl >> 1)] = packbf2(p, pn);
        }
      }
    }
  }
  __syncthreads();          // ps2 ready; ks2 dead

  // ---- stage V transposed-packed: vs2[d][s/2] = pack(V[2s'][d], V[2s'+1][d]) ----
  for (int i = tid; i < 1280; i += 256){
    int rp = i >> 4, d4 = i & 15;
    float4 v0 = *(const float4*)&Vb[(2*rp)*64 + d4*4];
    float4 v1 = *(const float4*)&Vb[(2*rp+1)*64 + d4*4];
    vs2[(d4*4+0)*84 + rp] = packbf2(v0.x, v1.x);
    vs2[(d4*4+1)*84 + rp] = packbf2(v0.y, v1.y);
    vs2[(d4*4+2)*84 + rp] = packbf2(v0.z, v1.z);
    vs2[(d4*4+3)*84 + rp] = packbf2(v0.w, v1.w);
  }
  __syncthreads();

  // ---- phase B: Z = P @ V, K=160 (5 MFMA); wave w -> d-cols w*16.. ----
  {
    f32x4 zacc = {0.f,0.f,0.f,0.f};
#pragma unroll
    for (int ks = 0; ks < 5; ++ks){
      uint4 ap  = *(const uint4*)&ps2[nl*84 + ks*16 + q*4];
      uint4 bv4 = *(const uint4*)&vs2[(w*16+nl)*84 + ks*16 + q*4];
      zacc = mfma16(ap, bv4, zacc);
    }
#pragma unroll
    for (int r = 0; r < 4; ++r)
      zs[(q*4+r)*68 + w*16 + nl] = zacc[r];
  }
  __syncthreads();

  // ---- phase C: zo = Z@Wo + bo + x ----
  {
    f32x4 cacc = {0.f,0.f,0.f,0.f};
#pragma unroll
    for (int ks = 0; ks < 2; ++ks){
      float4 f0 = *(const float4*)&zs[nl*68 + ks*32 + q*8];
      float4 f1 = *(const float4*)&zs[nl*68 + ks*32 + q*8 + 4];
      uint4 a;
      a.x = packbf2(f0.x, f0.y); a.y = packbf2(f0.z, f0.w);
      a.z = packbf2(f1.x, f1.y); a.w = packbf2(f1.z, f1.w);
      uint4 b = *(const uint4*)&wop[(w*16+nl)*32 + ks*16 + q*4];
      cacc = mfma16(a, b, cacc);
    }
    int col = w*16 + nl;
    float bov = bo[col];
#pragma unroll
    for (int r = 0; r < 4; ++r){
      int row = q*4 + r;
      int grow = bp*SS + t0 + row;
      zos[row*68 + col] = cacc[r] + bov + x[grow*64 + col];
    }
  }
  __syncthreads();

  // ---- LN1 -> os (fp32) + os2 (packed bf16) ----
  {
    float h[4], s8v[8];
#pragma unroll
    for (int j = 0; j < 4; ++j){
      int r = w + 4*j;
      h[j] = zos[r*68 + lane];
      s8v[j] = h[j]; s8v[4+j] = h[j]*h[j];
    }
    wred_sum_n<8>(s8v);
    float gl = g1[lane], bl = b1l[lane];
#pragma unroll
    for (int j = 0; j < 4; ++j){
      int r = w + 4*j;
      float mu = s8v[j]*(1.f/64.f);
      float var = s8v[4+j]*(1.f/64.f) - mu*mu;
      float o = gl*(h[j]-mu)*rsqrtf(fmaxf(var,0.f) + 1e-6f) + bl;
      os[r*68 + lane] = o;
      float on = __shfl_xor(o, 1, 64);
      if (!(lane & 1)) os2[r*36 + (lane >> 1)] = packbf2(o, on);
    }
  }
  __syncthreads();

  // ---- FFN1: a = relu(os@W1+b1); wave w -> n-tiles w*4..w*4+3 ----
  {
    uint4 ao0 = *(const uint4*)&os2[nl*36 + q*4];
    uint4 ao1 = *(const uint4*)&os2[nl*36 + 16 + q*4];
    f32x4 fa[4];
#pragma unroll
    for (int i = 0; i < 4; ++i){
      fa[i] = (f32x4){0.f,0.f,0.f,0.f};
      int n = (w*4+i)*16 + nl;
      uint4 b0 = *(const uint4*)&w1p[n*32 + q*4];
      uint4 b1v = *(const uint4*)&w1p[n*32 + 16 + q*4];
      fa[i] = mfma16(ao0, b0, fa[i]);
      fa[i] = mfma16(ao1, b1v, fa[i]);
    }
#pragma unroll
    for (int i = 0; i < 4; ++i){
      int n = (w*4+i)*16 + nl;
      float b1b = b1[n];
#pragma unroll
      for (int r = 0; r < 4; ++r){
        float a_ = fmaxf(fa[i][r] + b1b, 0.f);
        float an = __shfl_xor(a_, 1, 64);
        if (!(nl & 1))
          as2[(q*4+r)*132 + w*32 + i*8 + (nl >> 1)] = packbf2(a_, an);
      }
    }
  }
  __syncthreads();

  // ---- FFN2: r0 = a@W2 + b2 + os; wave w -> n-cols w*16.. ----
  {
    f32x4 f2 = {0.f,0.f,0.f,0.f};
#pragma unroll
    for (int ks = 0; ks < 8; ++ks){
      uint4 a = *(const uint4*)&as2[nl*132 + ks*16 + q*4];
      uint4 b = *(const uint4*)&w2p[(w*16+nl)*128 + ks*16 + q*4];
      f2 = mfma16(a, b, f2);
    }
    int col = w*16 + nl;
    float b2v = b2[col];
#pragma unroll
    for (int r = 0; r < 4; ++r){
      int row = q*4 + r;
      lnb[row*68 + col] = f2[r] + b2v + os[row*68 + col];
    }
  }
  __syncthreads();

  // ---- LN2 -> R, pred ----
  {
    float wfv = Wf[lane], bfv = bf[0];
    float h[4], s8v[8];
#pragma unroll
    for (int j = 0; j < 4; ++j){
      int r = w*4 + j;
      h[j] = lnb[r*68 + lane];
      s8v[j] = h[j]; s8v[4+j] = h[j]*h[j];
    }
    wred_sum_n<8>(s8v);
    float g2l = g2[lane], b2ll = b2l[lane];
    float pr[4];
#pragma unroll
    for (int j = 0; j < 4; ++j){
      int r = w*4 + j;
      float mu = s8v[j]*(1.f/64.f);
      float var = s8v[4+j]*(1.f/64.f) - mu*mu;
      float rv = g2l*(h[j]-mu)*rsqrtf(fmaxf(var,0.f) + 1e-6f) + b2ll;
      int grow = bp*SS + t0 + r;
      R[grow*64 + lane] = rv;
      pr[j] = rv * wfv;
    }
    wred_sum_n<4>(pr);
    if (lane == 0){
#pragma unroll
      for (int j = 0; j < 4; ++j){
        int grow = bp*SS + t0 + w*4 + j;
        pred[grow]  = pr[j] + bfv;
        predr[grow] = pr[j] + bfv;
      }
    }
  }
}

extern "C" void kernel_launch(void* const* d_in, const int* in_sizes, int n_in,
                              void* d_out, int out_size, void* d_ws, size_t ws_size,
                              hipStream_t stream){
  const float* inputs = (const float*)d_in[0];
  const float* Wp  = (const float*)d_in[2];
  const float* bpj = (const float*)d_in[3];
  const float* Wq  = (const float*)d_in[4];  const float* bq  = (const float*)d_in[5];
  const float* Wk  = (const float*)d_in[6];  const float* bk  = (const float*)d_in[7];
  const float* Wv  = (const float*)d_in[8];  const float* bv  = (const float*)d_in[9];
  const float* Wo  = (const float*)d_in[10]; const float* bo  = (const float*)d_in[11];
  const float* g1  = (const float*)d_in[12]; const float* b1l = (const float*)d_in[13];
  const float* W1  = (const float*)d_in[14]; const float* b1  = (const float*)d_in[15];
  const float* W2  = (const float*)d_in[16]; const float* b2  = (const float*)d_in[17];
  const float* g2  = (const float*)d_in[18]; const float* b2l = (const float*)d_in[19];
  const float* Wf  = (const float*)d_in[20]; const float* bf  = (const float*)d_in[21];

  float* outp = (float*)d_out;
  float* ws   = (float*)d_ws;
  float* x    = ws;                       // 819200 floats
  float* Qw   = ws + 819200;              // 819200 floats
  unsigned* wpack = (unsigned*)(ws + 1638400);  // 24576 u32
  const unsigned* wqkvp = wpack;          // wq,wk,wv
  const unsigned* wop   = wpack + 6144;
  const unsigned* w1p   = wpack + 8192;
  const unsigned* w2p   = wpack + 16384;

  float* pred  = outp + OFF_PRED;
  float* predr = outp + OFF_PREDR;
  float* Kc    = outp + OFF_K;
  float* Vc    = outp + OFF_V;
  float* Rr    = outp + OFF_R;
  float* attn  = outp + OFF_ATTN;

  k_pack<<<96, 256, 0, stream>>>(Wq, Wk, Wv, Wo, W1, W2, wpack);
  k_xqkv<<<NROW/16, 256, 0, stream>>>(inputs, Wp, bpj, wqkvp, bq, bk, bv,
                                      x, Qw, Kc, Vc);
  k_attn_ffn<<<dim3(NBP, 10), 256, 0, stream>>>(Qw, Kc, Vc, wop, w1p, w2p,
                                                bo, g1, b1l, x, b1, b2,
                                                g2, b2l, Wf, bf,
                                                attn, Rr, pred, predr);
}

// Round 10
// 131.561 us; speedup vs baseline: 1.2776x; 1.0504x over previous
//
#include <hip/hip_runtime.h>
#include <math.h>

#define BB 8
#define PP 10
#define SS 160
#define FXD 11
#define DD 64
#define DFF 256
#define NROW (BB*PP*SS)   /* 12800 */
#define NBP  (BB*PP)      /* 80 */

// d_out layout (floats): pred | pred_resampl | K | V | R | attn
#define OFF_PRED  0
#define OFF_PREDR 12800
#define OFF_K     25600
#define OFF_V     844800
#define OFF_R     1664000
#define OFF_ATTN  2483200

typedef short short8 __attribute__((ext_vector_type(8)));
typedef float f32x4  __attribute__((ext_vector_type(4)));

__device__ __forceinline__ void fma4(float4& acc, float s, const float4& b){
  acc.x += s*b.x; acc.y += s*b.y; acc.z += s*b.z; acc.w += s*b.w;
}
template<int N>
__device__ __forceinline__ void wred_sum_n(float (&v)[N]){
#pragma unroll
  for (int m = 32; m >= 1; m >>= 1){
#pragma unroll
    for (int i = 0; i < N; ++i) v[i] += __shfl_xor(v[i], m, 64);
  }
}
// quad-local (16-lane) reductions
template<int N>
__device__ __forceinline__ void qred_sum_n(float (&v)[N]){
#pragma unroll
  for (int m = 8; m >= 1; m >>= 1){
#pragma unroll
    for (int i = 0; i < N; ++i) v[i] += __shfl_xor(v[i], m, 64);
  }
}
template<int N>
__device__ __forceinline__ void qred_max_n(float (&v)[N]){
#pragma unroll
  for (int m = 8; m >= 1; m >>= 1){
#pragma unroll
    for (int i = 0; i < N; ++i) v[i] = fmaxf(v[i], __shfl_xor(v[i], m, 64));
  }
}
// bf16 pack (RTN-even)
__device__ __forceinline__ unsigned f2bf(float f){
  unsigned u = __float_as_uint(f);
  return (u + 0x7fffu + ((u >> 16) & 1u)) >> 16;
}
__device__ __forceinline__ unsigned packbf2(float x, float y){
  return f2bf(x) | (f2bf(y) << 16);
}
__device__ __forceinline__ f32x4 mfma16(uint4 a, uint4 b, f32x4 c){
  union { uint4 u; short8 s; } ua, ub;
  ua.u = a; ub.u = b;
  return __builtin_amdgcn_mfma_f32_16x16x32_bf16(ua.s, ub.s, c, 0, 0, 0);
}
__device__ __forceinline__ uint4 pack8(float4 a, float4 b){
  uint4 r;
  r.x = packbf2(a.x, a.y); r.y = packbf2(a.z, a.w);
  r.z = packbf2(b.x, b.y); r.w = packbf2(b.z, b.w);
  return r;
}

// ---------------------------------------------------------------------------
// proj (fp32) + QKV via MFMA with in-register B-frags from global fp32.
// Blocks 0..71 additionally pack Wo/W1/W2 into wpack (bf16 B-frag layout):
// wo@0 (64x32 u32), w1@2048 (256x32), w2@10240 (64x128). 800 blocks.
// ---------------------------------------------------------------------------
__global__ __launch_bounds__(256) void k_xqkv(const float* __restrict__ inp,
    const float* __restrict__ Wp, const float* __restrict__ bpj,
    const float* __restrict__ Wq, const float* __restrict__ bq,
    const float* __restrict__ Wk, const float* __restrict__ bk,
    const float* __restrict__ Wv, const float* __restrict__ bv,
    const float* __restrict__ Wo, const float* __restrict__ W1,
    const float* __restrict__ W2, unsigned* __restrict__ wpack,
    float* __restrict__ x, float* __restrict__ Q,
    float* __restrict__ Kc, float* __restrict__ Vc){
  __shared__ __align__(16) float ins[16*12];
  __shared__ __align__(16) unsigned xs2[16*36];
  int tid = threadIdx.x;
  int g = blockIdx.x;
  int row0 = g*16;
  // ---- weight pack for k_attn_ffn (blocks 0..71) ----
  {
    int pi = g*256 + tid;
    if (pi < 18432){
      const float* W; int N, K2, base, off;
      if (pi < 2048){ W = Wo; N = 64; K2 = 32; base = 0; off = pi; }
      else if (pi < 10240){ W = W1; N = 256; K2 = 32; base = 2048; off = pi - 2048; }
      else { W = W2; N = 64; K2 = 128; base = 10240; off = pi - 10240; }
      int n = off % N, k2 = off / N;
      wpack[base + n*K2 + k2] = packbf2(W[(2*k2)*N + n], W[(2*k2+1)*N + n]);
    }
  }
  // ---- stage inputs ----
  for (int i = tid; i < 16*FXD; i += 256){
    int r = i / FXD, f = i - r*FXD;
    ins[r*12 + f] = inp[row0*FXD + i];
  }
  __syncthreads();
  int tc = tid & 15, tr = tid >> 4;
  // ---- x = (inp @ Wp + bp) * 8 ----
  {
    float4 a = make_float4(0.f,0.f,0.f,0.f);
#pragma unroll
    for (int f = 0; f < FXD; ++f){
      float v = ins[tr*12 + f];
      float4 w4 = *(const float4*)&Wp[f*64 + tc*4];
      fma4(a, v, w4);
    }
    float4 bp4 = *(const float4*)&bpj[tc*4];
    float4 xv = make_float4((a.x+bp4.x)*8.f, (a.y+bp4.y)*8.f,
                            (a.z+bp4.z)*8.f, (a.w+bp4.w)*8.f);
    *(float4*)&x[(row0+tr)*64 + tc*4] = xv;
    xs2[tr*36 + tc*2]     = packbf2(xv.x, xv.y);
    xs2[tr*36 + tc*2 + 1] = packbf2(xv.z, xv.w);
  }
  __syncthreads();
  int lane = tid & 63, w = tid >> 6, nl = lane & 15, q = lane >> 4;
  uint4 a0 = *(const uint4*)&xs2[nl*36 + q*4];
  uint4 a1 = *(const uint4*)&xs2[nl*36 + 16 + q*4];
  int n = w*16 + nl;
  const float* Wm[3] = {Wq, Wk, Wv};
  const float* bias[3] = {bq, bk, bv};
  float* Out[3] = {Q, Kc, Vc};
#pragma unroll
  for (int mat = 0; mat < 3; ++mat){
    const float* W = Wm[mat];
    float w0 = W[(q*8+0)*64+n], w1 = W[(q*8+1)*64+n];
    float w2 = W[(q*8+2)*64+n], w3 = W[(q*8+3)*64+n];
    float w4 = W[(q*8+4)*64+n], w5 = W[(q*8+5)*64+n];
    float w6 = W[(q*8+6)*64+n], w7 = W[(q*8+7)*64+n];
    uint4 b0; b0.x = packbf2(w0,w1); b0.y = packbf2(w2,w3);
    b0.z = packbf2(w4,w5); b0.w = packbf2(w6,w7);
    float v0 = W[(32+q*8+0)*64+n], v1 = W[(32+q*8+1)*64+n];
    float v2 = W[(32+q*8+2)*64+n], v3 = W[(32+q*8+3)*64+n];
    float v4 = W[(32+q*8+4)*64+n], v5 = W[(32+q*8+5)*64+n];
    float v6 = W[(32+q*8+6)*64+n], v7 = W[(32+q*8+7)*64+n];
    uint4 b1; b1.x = packbf2(v0,v1); b1.y = packbf2(v2,v3);
    b1.z = packbf2(v4,v5); b1.w = packbf2(v6,v7);
    f32x4 acc = {0.f,0.f,0.f,0.f};
    acc = mfma16(a0, b0, acc);
    acc = mfma16(a1, b1, acc);
    float bvv = bias[mat][n];
    float* O = Out[mat];
#pragma unroll
    for (int r = 0; r < 4; ++r)
      O[(row0 + q*4 + r)*64 + n] = acc[r] + bvv;
  }
}

// ---------------------------------------------------------------------------
// Mega-fused attention+FFN, all matmuls MFMA. 16 t-rows/block, grid (80,10).
// Q/K/V fragments direct from global (L2). LDS 29.8KB -> 4 blocks/CU.
// Single-barrier online-softmax combine.
// ---------------------------------------------------------------------------
__global__ __launch_bounds__(256, 4) void k_attn_ffn(const float* __restrict__ Qg,
    const float* __restrict__ Kout, const float* __restrict__ Vout,
    const unsigned* __restrict__ wpack,
    const float* __restrict__ bo,
    const float* __restrict__ g1, const float* __restrict__ b1l,
    const float* __restrict__ x,
    const float* __restrict__ b1, const float* __restrict__ b2,
    const float* __restrict__ g2, const float* __restrict__ b2l,
    const float* __restrict__ Wf, const float* __restrict__ bf,
    float* __restrict__ attn, float* __restrict__ R,
    float* __restrict__ pred, float* __restrict__ predr){
  __shared__ __align__(16) unsigned char smA[5376];   // ps2 -> zos (overlay)
  unsigned* ps2 = (unsigned*)smA;                     // 16 x 84 u32
  float*    zos = (float*)smA;                        // 16 x 68 f
  __shared__ float mws[80], sws[80];
  __shared__ __align__(16) float zs[16*68];
  __shared__ __align__(16) float os[16*68];
  __shared__ __align__(16) unsigned os2[16*36];
  __shared__ __align__(16) unsigned as2[16*132];
  __shared__ __align__(16) float lnb[16*68];

  int tid = threadIdx.x;
  int bp = blockIdx.x, c = blockIdx.y;
  int t0 = c*16;
  const float* Kb = Kout + bp*(SS*DD);
  const float* Vb = Vout + bp*(SS*DD);
  const float* Qb = Qg + bp*(SS*DD);
  float* Ab = attn + bp*(SS*SS);
  const unsigned* wop = wpack;
  const unsigned* w1p = wpack + 2048;
  const unsigned* w2p = wpack + 10240;

  int lane = tid & 63, w = tid >> 6, nl = lane & 15, q = lane >> 4;

  // ---- phase A: logits via MFMA, Q/K frags direct from global ----
  int ntiles = (w < 2) ? 3 : 2;     // waves 0,1: tiles {w,w+4,w+8}; 2,3: {w,w+4}
  {
    const float* qr = &Qb[(t0+nl)*64];
    uint4 aq0 = pack8(*(const float4*)&qr[q*8],    *(const float4*)&qr[q*8+4]);
    uint4 aq1 = pack8(*(const float4*)&qr[32+q*8], *(const float4*)&qr[32+q*8+4]);
    float lg[3][4], ev[3][4];
    f32x4 pacc[3];
#pragma unroll
    for (int i = 0; i < 3; ++i){
      pacc[i] = (f32x4){0.f,0.f,0.f,0.f};
      if (i < ntiles){
        const float* kr = &Kb[((w+4*i)*16 + nl)*64];
        uint4 b0 = pack8(*(const float4*)&kr[q*8],    *(const float4*)&kr[q*8+4]);
        uint4 b1 = pack8(*(const float4*)&kr[32+q*8], *(const float4*)&kr[32+q*8+4]);
        pacc[i] = mfma16(aq0, b0, pacc[i]);
        pacc[i] = mfma16(aq1, b1, pacc[i]);
      }
    }
    float mw_[4];
#pragma unroll
    for (int r = 0; r < 4; ++r){
      int t = t0 + q*4 + r;
      float m_ = -1e30f;
#pragma unroll
      for (int i = 0; i < 3; ++i){
        if (i < ntiles){
          int s = (w + 4*i)*16 + nl;
          float l = (s <= t) ? pacc[i][r]*0.125f : -1e30f;
          lg[i][r] = l; m_ = fmaxf(m_, l);
        }
      }
      mw_[r] = m_;
    }
    qred_max_n<4>(mw_);
    float sw_[4];
#pragma unroll
    for (int r = 0; r < 4; ++r){
      float s_ = 0.f;
#pragma unroll
      for (int i = 0; i < 3; ++i){
        if (i < ntiles){
          float e = __expf(lg[i][r] - mw_[r]);
          ev[i][r] = e; s_ += e;
        }
      }
      sw_[r] = s_;
    }
    qred_sum_n<4>(sw_);
    if (nl == 0){
#pragma unroll
      for (int r = 0; r < 4; ++r){
        mws[(q*4+r)*5 + w] = mw_[r];
        sws[(q*4+r)*5 + w] = sw_[r];
      }
    }
    __syncthreads();
    float scale[4];
#pragma unroll
    for (int r = 0; r < 4; ++r){
      int row = q*4 + r;
      float m0 = mws[row*5+0], m1 = mws[row*5+1];
      float m2 = mws[row*5+2], m3 = mws[row*5+3];
      float gm = fmaxf(fmaxf(m0,m1), fmaxf(m2,m3));
      float tot = sws[row*5+0]*__expf(m0-gm) + sws[row*5+1]*__expf(m1-gm)
                + sws[row*5+2]*__expf(m2-gm) + sws[row*5+3]*__expf(m3-gm);
      scale[r] = __expf(mw_[r]-gm) / tot;
    }
#pragma unroll
    for (int i = 0; i < 3; ++i){
      if (i < ntiles){
        int s = (w + 4*i)*16 + nl;
#pragma unroll
        for (int r = 0; r < 4; ++r){
          float p_ = ev[i][r] * scale[r];
          Ab[(t0 + q*4 + r)*SS + s] = p_;
          float pn = __shfl_xor(p_, 1, 64);
          if (!(nl & 1))
            ps2[(q*4+r)*84 + (w+4*i)*8 + (nl >> 1)] = packbf2(p_, pn);
        }
      }
    }
  }
  __syncthreads();

  // ---- phase B: Z = P @ V (K=160, 5 MFMA); V frags direct from global ----
  {
    int d = w*16 + nl;
    f32x4 zacc = {0.f,0.f,0.f,0.f};
#pragma unroll
    for (int ks = 0; ks < 5; ++ks){
      int sb = ks*32 + q*8;
      uint4 bv;
      bv.x = packbf2(Vb[(sb+0)*64+d], Vb[(sb+1)*64+d]);
      bv.y = packbf2(Vb[(sb+2)*64+d], Vb[(sb+3)*64+d]);
      bv.z = packbf2(Vb[(sb+4)*64+d], Vb[(sb+5)*64+d]);
      bv.w = packbf2(Vb[(sb+6)*64+d], Vb[(sb+7)*64+d]);
      uint4 ap = *(const uint4*)&ps2[nl*84 + ks*16 + q*4];
      zacc = mfma16(ap, bv, zacc);
    }
#pragma unroll
    for (int r = 0; r < 4; ++r)
      zs[(q*4+r)*68 + d] = zacc[r];
  }
  __syncthreads();

  // ---- phase C: zo = Z@Wo + bo + x (zos overlays ps2 region) ----
  {
    f32x4 cacc = {0.f,0.f,0.f,0.f};
#pragma unroll
    for (int ks = 0; ks < 2; ++ks){
      float4 f0 = *(const float4*)&zs[nl*68 + ks*32 + q*8];
      float4 f1 = *(const float4*)&zs[nl*68 + ks*32 + q*8 + 4];
      uint4 a = pack8(f0, f1);
      uint4 b = *(const uint4*)&wop[(w*16+nl)*32 + ks*16 + q*4];
      cacc = mfma16(a, b, cacc);
    }
    int col = w*16 + nl;
    float bov = bo[col];
#pragma unroll
    for (int r = 0; r < 4; ++r){
      int row = q*4 + r;
      int grow = bp*SS + t0 + row;
      zos[row*68 + col] = cacc[r] + bov + x[grow*64 + col];
    }
  }
  __syncthreads();

  // ---- LN1 -> os (fp32) + os2 (packed bf16) ----
  {
    float h[4], s8v[8];
#pragma unroll
    for (int j = 0; j < 4; ++j){
      int r = w + 4*j;
      h[j] = zos[r*68 + lane];
      s8v[j] = h[j]; s8v[4+j] = h[j]*h[j];
    }
    wred_sum_n<8>(s8v);
    float gl = g1[lane], bl = b1l[lane];
#pragma unroll
    for (int j = 0; j < 4; ++j){
      int r = w + 4*j;
      float mu = s8v[j]*(1.f/64.f);
      float var = s8v[4+j]*(1.f/64.f) - mu*mu;
      float o = gl*(h[j]-mu)*rsqrtf(fmaxf(var,0.f) + 1e-6f) + bl;
      os[r*68 + lane] = o;
      float on = __shfl_xor(o, 1, 64);
      if (!(lane & 1)) os2[r*36 + (lane >> 1)] = packbf2(o, on);
    }
  }
  __syncthreads();

  // ---- FFN1: a = relu(os@W1+b1); wave w -> n-tiles w*4..w*4+3 ----
  {
    uint4 ao0 = *(const uint4*)&os2[nl*36 + q*4];
    uint4 ao1 = *(const uint4*)&os2[nl*36 + 16 + q*4];
    f32x4 fa[4];
#pragma unroll
    for (int i = 0; i < 4; ++i){
      fa[i] = (f32x4){0.f,0.f,0.f,0.f};
      int n = (w*4+i)*16 + nl;
      uint4 b0 = *(const uint4*)&w1p[n*32 + q*4];
      uint4 b1v = *(const uint4*)&w1p[n*32 + 16 + q*4];
      fa[i] = mfma16(ao0, b0, fa[i]);
      fa[i] = mfma16(ao1, b1v, fa[i]);
    }
#pragma unroll
    for (int i = 0; i < 4; ++i){
      int n = (w*4+i)*16 + nl;
      float b1b = b1[n];
#pragma unroll
      for (int r = 0; r < 4; ++r){
        float a_ = fmaxf(fa[i][r] + b1b, 0.f);
        float an = __shfl_xor(a_, 1, 64);
        if (!(nl & 1))
          as2[(q*4+r)*132 + w*32 + i*8 + (nl >> 1)] = packbf2(a_, an);
      }
    }
  }
  __syncthreads();

  // ---- FFN2: r0 = a@W2 + b2 + os ----
  {
    f32x4 f2 = {0.f,0.f,0.f,0.f};
#pragma unroll
    for (int ks = 0; ks < 8; ++ks){
      uint4 a = *(const uint4*)&as2[nl*132 + ks*16 + q*4];
      uint4 b = *(const uint4*)&w2p[(w*16+nl)*128 + ks*16 + q*4];
      f2 = mfma16(a, b, f2);
    }
    int col = w*16 + nl;
    float b2v = b2[col];
#pragma unroll
    for (int r = 0; r < 4; ++r){
      int row = q*4 + r;
      lnb[row*68 + col] = f2[r] + b2v + os[row*68 + col];
    }
  }
  __syncthreads();

  // ---- LN2 -> R, pred ----
  {
    float wfv = Wf[lane], bfv = bf[0];
    float h[4], s8v[8];
#pragma unroll
    for (int j = 0; j < 4; ++j){
      int r = w*4 + j;
      h[j] = lnb[r*68 + lane];
      s8v[j] = h[j]; s8v[4+j] = h[j]*h[j];
    }
    wred_sum_n<8>(s8v);
    float g2l = g2[lane], b2ll = b2l[lane];
    float pr[4];
#pragma unroll
    for (int j = 0; j < 4; ++j){
      int r = w*4 + j;
      float mu = s8v[j]*(1.f/64.f);
      float var = s8v[4+j]*(1.f/64.f) - mu*mu;
      float rv = g2l*(h[j]-mu)*rsqrtf(fmaxf(var,0.f) + 1e-6f) + b2ll;
      int grow = bp*SS + t0 + r;
      R[grow*64 + lane] = rv;
      pr[j] = rv * wfv;
    }
    wred_sum_n<4>(pr);
    if (lane == 0){
#pragma unroll
      for (int j = 0; j < 4; ++j){
        int grow = bp*SS + t0 + w*4 + j;
        pred[grow]  = pr[j] + bfv;
        predr[grow] = pr[j] + bfv;
      }
    }
  }
}

extern "C" void kernel_launch(void* const* d_in, const int* in_sizes, int n_in,
                              void* d_out, int out_size, void* d_ws, size_t ws_size,
                              hipStream_t stream){
  const float* inputs = (const float*)d_in[0];
  const float* Wp  = (const float*)d_in[2];
  const float* bpj = (const float*)d_in[3];
  const float* Wq  = (const float*)d_in[4];  const float* bq  = (const float*)d_in[5];
  const float* Wk  = (const float*)d_in[6];  const float* bk  = (const float*)d_in[7];
  const float* Wv  = (const float*)d_in[8];  const float* bv  = (const float*)d_in[9];
  const float* Wo  = (const float*)d_in[10]; const float* bo  = (const float*)d_in[11];
  const float* g1  = (const float*)d_in[12]; const float* b1l = (const float*)d_in[13];
  const float* W1  = (const float*)d_in[14]; const float* b1  = (const float*)d_in[15];
  const float* W2  = (const float*)d_in[16]; const float* b2  = (const float*)d_in[17];
  const float* g2  = (const float*)d_in[18]; const float* b2l = (const float*)d_in[19];
  const float* Wf  = (const float*)d_in[20]; const float* bf  = (const float*)d_in[21];

  float* outp = (float*)d_out;
  float* ws   = (float*)d_ws;
  float* x    = ws;                       // 819200 floats
  float* Qw   = ws + 819200;              // 819200 floats
  unsigned* wpack = (unsigned*)(ws + 1638400);  // 18432 u32

  float* pred  = outp + OFF_PRED;
  float* predr = outp + OFF_PREDR;
  float* Kc    = outp + OFF_K;
  float* Vc    = outp + OFF_V;
  float* Rr    = outp + OFF_R;
  float* attn  = outp + OFF_ATTN;

  k_xqkv<<<NROW/16, 256, 0, stream>>>(inputs, Wp, bpj, Wq, bq, Wk, bk, Wv, bv,
                                      Wo, W1, W2, wpack, x, Qw, Kc, Vc);
  k_attn_ffn<<<dim3(NBP, 10), 256, 0, stream>>>(Qw, Kc, Vc, wpack,
                                                bo, g1, b1l, x, b1, b2,
                                                g2, b2l, Wf, bf,
                                                attn, Rr, pred, predr);
}

// Round 11
// 128.438 us; speedup vs baseline: 1.3087x; 1.0243x over previous
//
#include <hip/hip_runtime.h>
#include <math.h>

#define BB 8
#define PP 10
#define SS 160
#define FXD 11
#define DD 64
#define DFF 256
#define NROW (BB*PP*SS)   /* 12800 */
#define NBP  (BB*PP)      /* 80 */

// d_out layout (floats): pred | pred_resampl | K | V | R | attn
#define OFF_PRED  0
#define OFF_PREDR 12800
#define OFF_K     25600
#define OFF_V     844800
#define OFF_R     1664000
#define OFF_ATTN  2483200

typedef short short8 __attribute__((ext_vector_type(8)));
typedef float f32x4  __attribute__((ext_vector_type(4)));

__device__ __forceinline__ void fma4(float4& acc, float s, const float4& b){
  acc.x += s*b.x; acc.y += s*b.y; acc.z += s*b.z; acc.w += s*b.w;
}
template<int N>
__device__ __forceinline__ void wred_sum_n(float (&v)[N]){
#pragma unroll
  for (int m = 32; m >= 1; m >>= 1){
#pragma unroll
    for (int i = 0; i < N; ++i) v[i] += __shfl_xor(v[i], m, 64);
  }
}
// quad-local (16-lane) reductions
template<int N>
__device__ __forceinline__ void qred_sum_n(float (&v)[N]){
#pragma unroll
  for (int m = 8; m >= 1; m >>= 1){
#pragma unroll
    for (int i = 0; i < N; ++i) v[i] += __shfl_xor(v[i], m, 64);
  }
}
template<int N>
__device__ __forceinline__ void qred_max_n(float (&v)[N]){
#pragma unroll
  for (int m = 8; m >= 1; m >>= 1){
#pragma unroll
    for (int i = 0; i < N; ++i) v[i] = fmaxf(v[i], __shfl_xor(v[i], m, 64));
  }
}
// bf16 pack (RTN-even)
__device__ __forceinline__ unsigned f2bf(float f){
  unsigned u = __float_as_uint(f);
  return (u + 0x7fffu + ((u >> 16) & 1u)) >> 16;
}
__device__ __forceinline__ unsigned packbf2(float x, float y){
  return f2bf(x) | (f2bf(y) << 16);
}
__device__ __forceinline__ f32x4 mfma16(uint4 a, uint4 b, f32x4 c){
  union { uint4 u; short8 s; } ua, ub;
  ua.u = a; ub.u = b;
  return __builtin_amdgcn_mfma_f32_16x16x32_bf16(ua.s, ub.s, c, 0, 0, 0);
}
__device__ __forceinline__ uint4 pack8(float4 a, float4 b){
  uint4 r;
  r.x = packbf2(a.x, a.y); r.y = packbf2(a.z, a.w);
  r.z = packbf2(b.x, b.y); r.w = packbf2(b.z, b.w);
  return r;
}

// ---------------------------------------------------------------------------
// proj (fp32) + QKV via MFMA (B-frags in-register from global fp32).
// Emits: x (fp32), Kc/Vc (fp32 outputs), Qp/Kp (bf16 packed along d,
// [row][32]u32 = A/B frag layout), Vp (bf16 packed along s, [bp][d][80]u32 =
// V^T B-frag layout). Blocks 0..71 also pack Wo/W1/W2 into wpack.
// ---------------------------------------------------------------------------
__global__ __launch_bounds__(256) void k_xqkv(const float* __restrict__ inp,
    const float* __restrict__ Wp, const float* __restrict__ bpj,
    const float* __restrict__ Wq, const float* __restrict__ bq,
    const float* __restrict__ Wk, const float* __restrict__ bk,
    const float* __restrict__ Wv, const float* __restrict__ bv,
    const float* __restrict__ Wo, const float* __restrict__ W1,
    const float* __restrict__ W2, unsigned* __restrict__ wpack,
    float* __restrict__ x, unsigned* __restrict__ Qp,
    unsigned* __restrict__ Kp, unsigned* __restrict__ Vp,
    float* __restrict__ Kc, float* __restrict__ Vc){
  __shared__ __align__(16) float ins[16*12];
  __shared__ __align__(16) unsigned xs2[16*36];
  int tid = threadIdx.x;
  int g = blockIdx.x;
  int row0 = g*16;
  // ---- weight pack for k_attn_ffn (blocks 0..71) ----
  {
    int pi = g*256 + tid;
    if (pi < 18432){
      const float* W; int N, K2, base, off;
      if (pi < 2048){ W = Wo; N = 64; K2 = 32; base = 0; off = pi; }
      else if (pi < 10240){ W = W1; N = 256; K2 = 32; base = 2048; off = pi - 2048; }
      else { W = W2; N = 64; K2 = 128; base = 10240; off = pi - 10240; }
      int n = off % N, k2 = off / N;
      wpack[base + n*K2 + k2] = packbf2(W[(2*k2)*N + n], W[(2*k2+1)*N + n]);
    }
  }
  // ---- stage inputs ----
  for (int i = tid; i < 16*FXD; i += 256){
    int r = i / FXD, f = i - r*FXD;
    ins[r*12 + f] = inp[row0*FXD + i];
  }
  __syncthreads();
  int tc = tid & 15, tr = tid >> 4;
  // ---- x = (inp @ Wp + bp) * 8 ----
  {
    float4 a = make_float4(0.f,0.f,0.f,0.f);
#pragma unroll
    for (int f = 0; f < FXD; ++f){
      float v = ins[tr*12 + f];
      float4 w4 = *(const float4*)&Wp[f*64 + tc*4];
      fma4(a, v, w4);
    }
    float4 bp4 = *(const float4*)&bpj[tc*4];
    float4 xv = make_float4((a.x+bp4.x)*8.f, (a.y+bp4.y)*8.f,
                            (a.z+bp4.z)*8.f, (a.w+bp4.w)*8.f);
    *(float4*)&x[(row0+tr)*64 + tc*4] = xv;
    xs2[tr*36 + tc*2]     = packbf2(xv.x, xv.y);
    xs2[tr*36 + tc*2 + 1] = packbf2(xv.z, xv.w);
  }
  __syncthreads();
  int lane = tid & 63, w = tid >> 6, nl = lane & 15, q = lane >> 4;
  uint4 a0 = *(const uint4*)&xs2[nl*36 + q*4];
  uint4 a1 = *(const uint4*)&xs2[nl*36 + 16 + q*4];
  int n = w*16 + nl;
  bool evenlane = !(lane & 1);
  int bpg = g / 10, loc0 = (g - bpg*10)*16;     // bp, local t base
  const float* Wm[3] = {Wq, Wk, Wv};
  const float* bias[3] = {bq, bk, bv};
#pragma unroll
  for (int mat = 0; mat < 3; ++mat){
    const float* W = Wm[mat];
    float w0 = W[(q*8+0)*64+n], w1 = W[(q*8+1)*64+n];
    float w2 = W[(q*8+2)*64+n], w3 = W[(q*8+3)*64+n];
    float w4 = W[(q*8+4)*64+n], w5 = W[(q*8+5)*64+n];
    float w6 = W[(q*8+6)*64+n], w7 = W[(q*8+7)*64+n];
    uint4 b0; b0.x = packbf2(w0,w1); b0.y = packbf2(w2,w3);
    b0.z = packbf2(w4,w5); b0.w = packbf2(w6,w7);
    float v0 = W[(32+q*8+0)*64+n], v1 = W[(32+q*8+1)*64+n];
    float v2 = W[(32+q*8+2)*64+n], v3 = W[(32+q*8+3)*64+n];
    float v4 = W[(32+q*8+4)*64+n], v5 = W[(32+q*8+5)*64+n];
    float v6 = W[(32+q*8+6)*64+n], v7 = W[(32+q*8+7)*64+n];
    uint4 b1; b1.x = packbf2(v0,v1); b1.y = packbf2(v2,v3);
    b1.z = packbf2(v4,v5); b1.w = packbf2(v6,v7);
    f32x4 acc = {0.f,0.f,0.f,0.f};
    acc = mfma16(a0, b0, acc);
    acc = mfma16(a1, b1, acc);
    float bvv = bias[mat][n];
    float o[4];
#pragma unroll
    for (int r = 0; r < 4; ++r) o[r] = acc[r] + bvv;
    if (mat == 0){
      // Qp packed along d
#pragma unroll
      for (int r = 0; r < 4; ++r){
        float on = __shfl_xor(o[r], 1, 64);
        if (evenlane) Qp[(row0 + q*4 + r)*32 + (n >> 1)] = packbf2(o[r], on);
      }
    } else if (mat == 1){
#pragma unroll
      for (int r = 0; r < 4; ++r){
        Kc[(row0 + q*4 + r)*64 + n] = o[r];
        float on = __shfl_xor(o[r], 1, 64);
        if (evenlane) Kp[(row0 + q*4 + r)*32 + (n >> 1)] = packbf2(o[r], on);
      }
    } else {
#pragma unroll
      for (int r = 0; r < 4; ++r)
        Vc[(row0 + q*4 + r)*64 + n] = o[r];
      // Vp packed along s (pairs of rows live in this thread)
      unsigned* vd = &Vp[bpg*(64*80) + n*80 + (loc0 >> 1) + q*2];
      vd[0] = packbf2(o[0], o[1]);
      vd[1] = packbf2(o[2], o[3]);
    }
  }
}

// ---------------------------------------------------------------------------
// Mega-fused attention+FFN, all matmuls MFMA. 16 t-rows/block, grid (80,10).
// Only live causal tiles computed (tiles 0..c); dead attn columns zero-filled
// with float4 stores. Q/K/V read pre-packed (Qp/Kp/Vp). LDS ~30KB, 4 blk/CU.
// ---------------------------------------------------------------------------
__global__ __launch_bounds__(256, 4) void k_attn_ffn(
    const unsigned* __restrict__ Qp, const unsigned* __restrict__ Kp,
    const unsigned* __restrict__ Vp, const unsigned* __restrict__ wpack,
    const float* __restrict__ bo,
    const float* __restrict__ g1, const float* __restrict__ b1l,
    const float* __restrict__ x,
    const float* __restrict__ b1, const float* __restrict__ b2,
    const float* __restrict__ g2, const float* __restrict__ b2l,
    const float* __restrict__ Wf, const float* __restrict__ bf,
    float* __restrict__ attn, float* __restrict__ R,
    float* __restrict__ pred, float* __restrict__ predr){
  __shared__ __align__(16) unsigned char smA[5376];   // ps2 -> zos (overlay)
  unsigned* ps2 = (unsigned*)smA;                     // 16 x 84 u32
  float*    zos = (float*)smA;                        // 16 x 68 f
  __shared__ float mws[80], sws[80];
  __shared__ __align__(16) float zs[16*68];
  __shared__ __align__(16) float os[16*68];
  __shared__ __align__(16) unsigned os2[16*36];
  __shared__ __align__(16) unsigned as2[16*132];
  __shared__ __align__(16) float lnb[16*68];

  int tid = threadIdx.x;
  int bp = blockIdx.x, c = blockIdx.y;
  int t0 = c*16;
  float* Ab = attn + bp*(SS*SS);
  const unsigned* wop = wpack;
  const unsigned* w1p = wpack + 2048;
  const unsigned* w2p = wpack + 10240;

  int lane = tid & 63, w = tid >> 6, nl = lane & 15, q = lane >> 4;

  // ---- zero-fill dead attn columns (tiles > c): s in [(c+1)*16, 160) ----
  {
    int zc0 = (c+1)*16;
    int zcw = 160 - zc0;                    // multiple of 16 (0 when c=9)
    int nq = (16*zcw) >> 2;                 // float4 count
    int perrow = zcw >> 2;
    for (int i = tid; i < nq; i += 256){
      int r = i / perrow, col = zc0 + (i - r*perrow)*4;
      *(float4*)&Ab[(t0 + r)*SS + col] = make_float4(0.f,0.f,0.f,0.f);
    }
    // zero the ps2 pad tile when phase-B K-step overshoots ((c+1) odd <=> c even)
    if (!(c & 1) && tid < 128){
      int r = tid >> 3, j = tid & 7;
      ps2[r*84 + (c+1)*8 + j] = 0;
    }
  }

  // ---- phase A: logits via MFMA over live tiles only ----
  int ntiles = (w <= c) ? (((c - w) >> 2) + 1) : 0;   // wave w: tiles w,w+4,w+8 <= c
  {
    const unsigned* qpr = &Qp[(bp*SS + t0 + nl)*32];
    uint4 aq0 = *(const uint4*)&qpr[q*4];
    uint4 aq1 = *(const uint4*)&qpr[16 + q*4];
    float lg[3][4], ev[3][4];
    f32x4 pacc[3];
#pragma unroll
    for (int i = 0; i < 3; ++i){
      pacc[i] = (f32x4){0.f,0.f,0.f,0.f};
      if (i < ntiles){
        const unsigned* kpr = &Kp[(bp*SS + (w+4*i)*16 + nl)*32];
        uint4 b0 = *(const uint4*)&kpr[q*4];
        uint4 b1 = *(const uint4*)&kpr[16 + q*4];
        pacc[i] = mfma16(aq0, b0, pacc[i]);
        pacc[i] = mfma16(aq1, b1, pacc[i]);
      }
    }
    float mw_[4];
#pragma unroll
    for (int r = 0; r < 4; ++r){
      int t = t0 + q*4 + r;
      float m_ = -1e30f;
#pragma unroll
      for (int i = 0; i < 3; ++i){
        if (i < ntiles){
          int s = (w + 4*i)*16 + nl;
          float l = (s <= t) ? pacc[i][r]*0.125f : -1e30f;
          lg[i][r] = l; m_ = fmaxf(m_, l);
        }
      }
      mw_[r] = m_;
    }
    qred_max_n<4>(mw_);
    float sw_[4];
#pragma unroll
    for (int r = 0; r < 4; ++r){
      float s_ = 0.f;
#pragma unroll
      for (int i = 0; i < 3; ++i){
        if (i < ntiles){
          float e = __expf(lg[i][r] - mw_[r]);
          ev[i][r] = e; s_ += e;
        }
      }
      sw_[r] = s_;
    }
    qred_sum_n<4>(sw_);
    if (nl == 0){
#pragma unroll
      for (int r = 0; r < 4; ++r){
        mws[(q*4+r)*5 + w] = mw_[r];
        sws[(q*4+r)*5 + w] = sw_[r];
      }
    }
    __syncthreads();
    float scale[4];
#pragma unroll
    for (int r = 0; r < 4; ++r){
      int row = q*4 + r;
      float m0 = mws[row*5+0], m1 = mws[row*5+1];
      float m2 = mws[row*5+2], m3 = mws[row*5+3];
      float gm = fmaxf(fmaxf(m0,m1), fmaxf(m2,m3));
      float tot = sws[row*5+0]*__expf(m0-gm) + sws[row*5+1]*__expf(m1-gm)
                + sws[row*5+2]*__expf(m2-gm) + sws[row*5+3]*__expf(m3-gm);
      scale[r] = __expf(mw_[r]-gm) / tot;
    }
#pragma unroll
    for (int i = 0; i < 3; ++i){
      if (i < ntiles){
        int s = (w + 4*i)*16 + nl;
#pragma unroll
        for (int r = 0; r < 4; ++r){
          float p_ = ev[i][r] * scale[r];
          Ab[(t0 + q*4 + r)*SS + s] = p_;
          float pn = __shfl_xor(p_, 1, 64);
          if (!(nl & 1))
            ps2[(q*4+r)*84 + (w+4*i)*8 + (nl >> 1)] = packbf2(p_, pn);
        }
      }
    }
  }
  __syncthreads();

  // ---- phase B: Z = P @ V over live K-range; V frags pre-packed ----
  {
    int nks = (c + 2) >> 1;                 // 32-wide K steps needed
    int d = w*16 + nl;
    const unsigned* vpd = &Vp[bp*(64*80) + d*80];
    f32x4 zacc = {0.f,0.f,0.f,0.f};
#pragma unroll
    for (int ks = 0; ks < 5; ++ks){
      if (ks < nks){
        uint4 bv = *(const uint4*)&vpd[ks*16 + q*4];
        uint4 ap = *(const uint4*)&ps2[nl*84 + ks*16 + q*4];
        zacc = mfma16(ap, bv, zacc);
      }
    }
#pragma unroll
    for (int r = 0; r < 4; ++r)
      zs[(q*4+r)*68 + d] = zacc[r];
  }
  __syncthreads();

  // ---- phase C: zo = Z@Wo + bo + x (zos overlays ps2 region) ----
  {
    f32x4 cacc = {0.f,0.f,0.f,0.f};
#pragma unroll
    for (int ks = 0; ks < 2; ++ks){
      float4 f0 = *(const float4*)&zs[nl*68 + ks*32 + q*8];
      float4 f1 = *(const float4*)&zs[nl*68 + ks*32 + q*8 + 4];
      uint4 a = pack8(f0, f1);
      uint4 b = *(const uint4*)&wop[(w*16+nl)*32 + ks*16 + q*4];
      cacc = mfma16(a, b, cacc);
    }
    int col = w*16 + nl;
    float bov = bo[col];
#pragma unroll
    for (int r = 0; r < 4; ++r){
      int row = q*4 + r;
      int grow = bp*SS + t0 + row;
      zos[row*68 + col] = cacc[r] + bov + x[grow*64 + col];
    }
  }
  __syncthreads();

  // ---- LN1 -> os (fp32) + os2 (packed bf16) ----
  {
    float h[4], s8v[8];
#pragma unroll
    for (int j = 0; j < 4; ++j){
      int r = w + 4*j;
      h[j] = zos[r*68 + lane];
      s8v[j] = h[j]; s8v[4+j] = h[j]*h[j];
    }
    wred_sum_n<8>(s8v);
    float gl = g1[lane], bl = b1l[lane];
#pragma unroll
    for (int j = 0; j < 4; ++j){
      int r = w + 4*j;
      float mu = s8v[j]*(1.f/64.f);
      float var = s8v[4+j]*(1.f/64.f) - mu*mu;
      float o = gl*(h[j]-mu)*rsqrtf(fmaxf(var,0.f) + 1e-6f) + bl;
      os[r*68 + lane] = o;
      float on = __shfl_xor(o, 1, 64);
      if (!(lane & 1)) os2[r*36 + (lane >> 1)] = packbf2(o, on);
    }
  }
  __syncthreads();

  // ---- FFN1: a = relu(os@W1+b1); wave w -> n-tiles w*4..w*4+3 ----
  {
    uint4 ao0 = *(const uint4*)&os2[nl*36 + q*4];
    uint4 ao1 = *(const uint4*)&os2[nl*36 + 16 + q*4];
    f32x4 fa[4];
#pragma unroll
    for (int i = 0; i < 4; ++i){
      fa[i] = (f32x4){0.f,0.f,0.f,0.f};
      int n = (w*4+i)*16 + nl;
      uint4 b0 = *(const uint4*)&w1p[n*32 + q*4];
      uint4 b1v = *(const uint4*)&w1p[n*32 + 16 + q*4];
      fa[i] = mfma16(ao0, b0, fa[i]);
      fa[i] = mfma16(ao1, b1v, fa[i]);
    }
#pragma unroll
    for (int i = 0; i < 4; ++i){
      int n = (w*4+i)*16 + nl;
      float b1b = b1[n];
#pragma unroll
      for (int r = 0; r < 4; ++r){
        float a_ = fmaxf(fa[i][r] + b1b, 0.f);
        float an = __shfl_xor(a_, 1, 64);
        if (!(nl & 1))
          as2[(q*4+r)*132 + w*32 + i*8 + (nl >> 1)] = packbf2(a_, an);
      }
    }
  }
  __syncthreads();

  // ---- FFN2: r0 = a@W2 + b2 + os ----
  {
    f32x4 f2 = {0.f,0.f,0.f,0.f};
#pragma unroll
    for (int ks = 0; ks < 8; ++ks){
      uint4 a = *(const uint4*)&as2[nl*132 + ks*16 + q*4];
      uint4 b = *(const uint4*)&w2p[(w*16+nl)*128 + ks*16 + q*4];
      f2 = mfma16(a, b, f2);
    }
    int col = w*16 + nl;
    float b2v = b2[col];
#pragma unroll
    for (int r = 0; r < 4; ++r){
      int row = q*4 + r;
      lnb[row*68 + col] = f2[r] + b2v + os[row*68 + col];
    }
  }
  __syncthreads();

  // ---- LN2 -> R, pred ----
  {
    float wfv = Wf[lane], bfv = bf[0];
    float h[4], s8v[8];
#pragma unroll
    for (int j = 0; j < 4; ++j){
      int r = w*4 + j;
      h[j] = lnb[r*68 + lane];
      s8v[j] = h[j]; s8v[4+j] = h[j]*h[j];
    }
    wred_sum_n<8>(s8v);
    float g2l = g2[lane], b2ll = b2l[lane];
    float pr[4];
#pragma unroll
    for (int j = 0; j < 4; ++j){
      int r = w*4 + j;
      float mu = s8v[j]*(1.f/64.f);
      float var = s8v[4+j]*(1.f/64.f) - mu*mu;
      float rv = g2l*(h[j]-mu)*rsqrtf(fmaxf(var,0.f) + 1e-6f) + b2ll;
      int grow = bp*SS + t0 + r;
      R[grow*64 + lane] = rv;
      pr[j] = rv * wfv;
    }
    wred_sum_n<4>(pr);
    if (lane == 0){
#pragma unroll
      for (int j = 0; j < 4; ++j){
        int grow = bp*SS + t0 + w*4 + j;
        pred[grow]  = pr[j] + bfv;
        predr[grow] = pr[j] + bfv;
      }
    }
  }
}

extern "C" void kernel_launch(void* const* d_in, const int* in_sizes, int n_in,
                              void* d_out, int out_size, void* d_ws, size_t ws_size,
                              hipStream_t stream){
  const float* inputs = (const float*)d_in[0];
  const float* Wp  = (const float*)d_in[2];
  const float* bpj = (const float*)d_in[3];
  const float* Wq  = (const float*)d_in[4];  const float* bq  = (const float*)d_in[5];
  const float* Wk  = (const float*)d_in[6];  const float* bk  = (const float*)d_in[7];
  const float* Wv  = (const float*)d_in[8];  const float* bv  = (const float*)d_in[9];
  const float* Wo  = (const float*)d_in[10]; const float* bo  = (const float*)d_in[11];
  const float* g1  = (const float*)d_in[12]; const float* b1l = (const float*)d_in[13];
  const float* W1  = (const float*)d_in[14]; const float* b1  = (const float*)d_in[15];
  const float* W2  = (const float*)d_in[16]; const float* b2  = (const float*)d_in[17];
  const float* g2  = (const float*)d_in[18]; const float* b2l = (const float*)d_in[19];
  const float* Wf  = (const float*)d_in[20]; const float* bf  = (const float*)d_in[21];

  float* outp = (float*)d_out;
  float* ws   = (float*)d_ws;
  float* x    = ws;                               // 819200 floats
  unsigned* Qp = (unsigned*)(ws + 819200);        // 409600 u32
  unsigned* Kp = Qp + 409600;                     // 409600 u32
  unsigned* Vp = Kp + 409600;                     // 409600 u32
  unsigned* wpack = Vp + 409600;                  // 18432 u32

  float* pred  = outp + OFF_PRED;
  float* predr = outp + OFF_PREDR;
  float* Kc    = outp + OFF_K;
  float* Vc    = outp + OFF_V;
  float* Rr    = outp + OFF_R;
  float* attn  = outp + OFF_ATTN;

  k_xqkv<<<NROW/16, 256, 0, stream>>>(inputs, Wp, bpj, Wq, bq, Wk, bk, Wv, bv,
                                      Wo, W1, W2, wpack, x, Qp, Kp, Vp, Kc, Vc);
  k_attn_ffn<<<dim3(NBP, 10), 256, 0, stream>>>(Qp, Kp, Vp, wpack,
                                                bo, g1, b1l, x, b1, b2,
                                                g2, b2l, Wf, bf,
                                                attn, Rr, pred, predr);
}